// Round 16
// baseline (842.929 us; speedup 1.0000x reference)
//
#include <hip/hip_runtime.h>
#include <math.h>

#define BB 32
#define TT 832
#define DD 256
#define NLAYER 4
#define NH 4
#define HDIM 64
#define FF 1024
#define SS 3
#define LMM 36
#define BT (BB*TT)      // 26624
#define NQ 192
#define NHID 64

typedef unsigned short u16;
typedef __attribute__((ext_vector_type(8))) short bf16x8;   // 8 bf16 (4 VGPR)
typedef __attribute__((ext_vector_type(4))) float f32x4;    // 4 fp32

// Hardware bf16 convert (RNE). 1 VALU op.
__device__ __forceinline__ u16 f2bf(float f) {
    unsigned r;
    asm("v_cvt_pk_bf16_f32 %0, %1, %1" : "=v"(r) : "v"(f));
    return (u16)r;
}
__device__ __forceinline__ float bf2f(u16 b) {
    return __builtin_bit_cast(float, (unsigned)b << 16);
}

__device__ __forceinline__ void gload_lds16(const void* g, void* l) {
    __builtin_amdgcn_global_load_lds(
        (const __attribute__((address_space(1))) unsigned int*)g,
        (__attribute__((address_space(3))) unsigned int*)l, 16, 0, 0);
}

// gelu(tanh approx): 0.5x(1+tanh z) == x * sigmoid(2z), z = 0.79788456(x+0.044715x^3)
// 2z = x*(1.5957691216 + 0.0713548162 x^2). ~8 VALU ops vs ~12 for tanh form.
static __device__ __forceinline__ float gelu_tanh(float x) {
    float z2 = x * (1.5957691216057308f + 0.07135481624214252f * x * x);
    return x / (1.f + __expf(-z2));
}

// ---------------------------------------------------------------------------
// Merged weight convert+transpose + bias concat. One launch, 3468 blocks.
// ---------------------------------------------------------------------------
__global__ __launch_bounds__(256) void wtrans_all(
    const float* __restrict__ wq, const float* __restrict__ wk,
    const float* __restrict__ wv, const float* __restrict__ wo,
    const float* __restrict__ w1, const float* __restrict__ w2,
    const float* __restrict__ ma_wq, const float* __restrict__ ma_wo,
    const float* __restrict__ ha_w1, const float* __restrict__ ha_w2,
    const float* __restrict__ hv_w1, const float* __restrict__ hv_w2,
    const float* __restrict__ bq, const float* __restrict__ bk,
    const float* __restrict__ bv,
    u16* __restrict__ Wqkv, u16* __restrict__ Wo_, u16* __restrict__ W1t,
    u16* __restrict__ W2t, u16* __restrict__ Wmq, u16* __restrict__ Wmo,
    u16* __restrict__ Wha1, u16* __restrict__ Wha2,
    u16* __restrict__ Whv1, u16* __restrict__ Whv2,
    float* __restrict__ bqkv)
{
    __shared__ float tile[32][33];
    int bid = blockIdx.x;
    int t = threadIdx.x;
    if (bid >= 3456) {
        int i = (bid - 3456) * 256 + t;       // [0, NL*768)
        int l = i / 768, j = i - l * 768;
        float v = (j < 256) ? bq[l*256 + j]
                : (j < 512) ? bk[l*256 + j - 256]
                            : bv[l*256 + j - 512];
        bqkv[i] = v;
        return;
    }
    const float* src; u16* dst; int K, N, row0, nrows, bx, by, l;
    if (bid < 1024) {
        int job = bid >> 8, local = bid & 255;
        bx = local & 7; by = (local >> 3) & 7; l = local >> 6;
        K = 256; N = 256;
        nrows = (job < 3) ? 768 : 256;
        row0  = (job < 3) ? job * 256 : 0;
        src = (job == 0) ? wq : (job == 1) ? wk : (job == 2) ? wv : wo;
        dst = (job < 3) ? Wqkv : Wo_;
    } else if (bid < 2048) {
        int local = bid - 1024;
        bx = local & 31; by = (local >> 5) & 7; l = local >> 8;
        K = 256; N = 1024; row0 = 0; nrows = 1024; src = w1; dst = W1t;
    } else if (bid < 3072) {
        int local = bid - 2048;
        bx = local & 7; by = (local >> 3) & 31; l = local >> 8;
        K = 1024; N = 256; row0 = 0; nrows = 256; src = w2; dst = W2t;
    } else {
        int local = bid - 3072;               // 0..383
        int which = local >> 6;               // 0..5
        int loc2 = local & 63;
        bx = loc2 & 7; by = loc2 >> 3; l = 0;
        K = 256; N = 256; row0 = 0; nrows = 256;
        const float* srcs[6] = {ma_wq, ma_wo, ha_w1, ha_w2, hv_w1, hv_w2};
        u16* dsts[6] = {Wmq, Wmo, Wha1, Wha2, Whv1, Whv2};
        src = srcs[which];
        dst = dsts[which];
    }
    int n0 = bx * 32, k0 = by * 32;
    const float* s = src + (size_t)l * K * N;
    u16* d = dst + (size_t)l * nrows * K;
    int r = t >> 3, c4 = (t & 7) * 4;
    float4 v = *(const float4*)(s + (size_t)(k0 + r) * N + n0 + c4);
    tile[r][c4+0] = v.x; tile[r][c4+1] = v.y; tile[r][c4+2] = v.z; tile[r][c4+3] = v.w;
    __syncthreads();
    int nr = t >> 3, kc4 = (t & 7) * 4;
    ushort4 o;
    o.x = f2bf(tile[kc4+0][nr]); o.y = f2bf(tile[kc4+1][nr]);
    o.z = f2bf(tile[kc4+2][nr]); o.w = f2bf(tile[kc4+3][nr]);
    *(ushort4*)(d + (size_t)(row0 + n0 + nr) * K + k0 + kc4) = o;
}

// ---------------------------------------------------------------------------
// bf16 MFMA GEMM: C[M,N] = act(A[M,K]@W + bias) (+res). Wt is [N][K] bf16.
// BM=128, BN=NF*32, BK=64, 4 waves (2x2), 16x16x32 mfma, swizzled LDS,
// XCD swizzle over 1-D grid (nbx%8==0). __launch_bounds__(256,5): 32KB LDS
// permits 5 blocks/CU; VGPR cap 102 >= measured 88 (no spill).
// SCALEQ: cols [0,256) * 0.125*log2e. VOUT (NF=4 only): bnb>=4 -> Vt.
// ---------------------------------------------------------------------------
template<int ACT, int RES, int OUTBF, int SCALEQ, int VOUT, int NF>
__global__ __launch_bounds__(256, 5) void gemm_bf16(
    const u16* __restrict__ A, int lda,
    const u16* __restrict__ Wt,
    const float* __restrict__ bias,
    const float* __restrict__ Rsd,
    void* __restrict__ Cout, int ldc, int K,
    u16* __restrict__ Vtout, int nbx)
{
    constexpr int BN = NF * 32;
    __shared__ u16 SMEM[128*64 + BN*64];
    u16* As = SMEM;
    u16* Bs = SMEM + 128*64;
    const int t = threadIdx.x, w = t >> 6;
    const int lane = t & 63, lo = lane & 15, hi = lane >> 4;
    const int kblk = blockIdx.x;
    const int xcd = kblk & 7;
    const int j = kblk >> 3;
    const int chunk = nbx >> 3;
    const int bmb = xcd * chunk + j % chunk;
    const int bnb = j / chunk;
    const int bm = bmb * 128, bn = bnb * BN;
    const int wr = w >> 1, wc = w & 1;
    f32x4 acc[4][NF] = {};

    for (int k0 = 0; k0 < K; k0 += 64) {
        __syncthreads();
        #pragma unroll
        for (int i = 0; i < 4; ++i) {
            int id = i*256 + t;
            int row = id >> 3, c = id & 7, cs = c ^ (row & 7);
            gload_lds16(A + (size_t)(bm + row) * lda + k0 + cs*8,
                        &As[(i*256 + w*64)*8]);
        }
        #pragma unroll
        for (int i = 0; i < BN/32; ++i) {
            int id = i*256 + t;
            int row = id >> 3, c = id & 7, cs = c ^ (row & 7);
            gload_lds16(Wt + (size_t)(bn + row) * K + k0 + cs*8,
                        &Bs[(i*256 + w*64)*8]);
        }
        __syncthreads();
        #pragma unroll
        for (int ks = 0; ks < 2; ++ks) {
            bf16x8 af[4], bfr[NF];
            #pragma unroll
            for (int m = 0; m < 4; ++m) {
                int row = wr*64 + m*16 + lo;
                af[m] = *(const bf16x8*)&As[row*64 + (((ks*4 + hi) ^ (row & 7)) * 8)];
            }
            #pragma unroll
            for (int n = 0; n < NF; ++n) {
                int row = wc*(NF*16) + n*16 + lo;
                bfr[n] = *(const bf16x8*)&Bs[row*64 + (((ks*4 + hi) ^ (row & 7)) * 8)];
            }
            #pragma unroll
            for (int m = 0; m < 4; ++m)
                #pragma unroll
                for (int n = 0; n < NF; ++n)
                    acc[m][n] = __builtin_amdgcn_mfma_f32_16x16x32_bf16(
                        af[m], bfr[n], acc[m][n], 0, 0, 0);
        }
    }
    float bv[NF];
    #pragma unroll
    for (int n = 0; n < NF; ++n) bv[n] = bias[bn + wc*(NF*16) + n*16 + lo];

    if constexpr (VOUT) {
        if (bnb >= 4) {
            // V columns: transpose through LDS, write Vt[b][h][d][t] directly.
            __syncthreads();             // done reading As/Bs
            u16* Vs = SMEM;              // [128 rows][128 cols]  (NF=4 only)
            #pragma unroll
            for (int m = 0; m < 4; ++m)
                #pragma unroll
                for (int r = 0; r < 4; ++r) {
                    int rowl = wr*64 + m*16 + hi*4 + r;
                    #pragma unroll
                    for (int n = 0; n < NF; ++n) {
                        int coll = wc*64 + n*16 + lo;
                        Vs[rowl*128 + coll] = f2bf(acc[m][n][r] + bv[n]);
                    }
                }
            __syncthreads();
            int c = t & 127;
            int g0 = (t >> 7) * 8;
            int hh = (bnb - 4) * 2 + (c >> 6);
            int dd = c & 63;
            #pragma unroll
            for (int g = g0; g < g0 + 8; ++g) {
                int tg = bm + g*8;           // 8-token group, single batch (832%8==0)
                int bb = tg / TT;
                int tloc = tg - bb*TT;
                u16 tmp[8];
                #pragma unroll
                for (int jj = 0; jj < 8; ++jj) tmp[jj] = Vs[(g*8 + jj)*128 + c];
                *(uint4*)(Vtout + ((size_t)((bb*NH + hh)*64 + dd)) * TT + tloc) =
                    *(uint4*)&tmp[0];
            }
            return;
        }
    }

    #pragma unroll
    for (int m = 0; m < 4; ++m) {
        #pragma unroll
        for (int r = 0; r < 4; ++r) {
            int grow = bm + wr*64 + m*16 + hi*4 + r;
            #pragma unroll
            for (int n = 0; n < NF; ++n) {
                int gcol = bn + wc*(NF*16) + n*16 + lo;
                float v = acc[m][n][r] + bv[n];
                if (ACT == 1) v = gelu_tanh(v);
                if (ACT == 2) v = (v > 0.f) ? v : 0.01f * v;
                if (SCALEQ) v = (gcol < 256) ? v * 0.18033688f : v;  // 0.125*log2(e)
                size_t off = (size_t)grow * ldc + gcol;
                if (RES) v += Rsd[off];
                if (OUTBF) ((u16*)Cout)[off] = f2bf(v);
                else       ((float*)Cout)[off] = v;
            }
        }
    }
}

// ---------------------------------------------------------------------------
// Full-row-width residual GEMM with fused LayerNorm epilogue (R8 v1, proven).
// N=256 fixed. X += A@Wt + bias (fp32); if LNOUT: Hb = LN(X_row)*ls+lb (bf16).
// BM=64, 4 waves, each wave owns 16 rows x 256 cols (acc[16] f32x4).
// Works for any M multiple of 64 (grid = M/64).
// ---------------------------------------------------------------------------
template<int LNOUT>
__global__ __launch_bounds__(256) void gemm_res_ln(
    const u16* __restrict__ A, int lda,
    const u16* __restrict__ Wt,                 // [256][K]
    const float* __restrict__ bias,
    float* __restrict__ X,                      // residual in/out (fp32)
    const float* __restrict__ ls, const float* __restrict__ lb,
    u16* __restrict__ Hb, int K)
{
    __shared__ u16 As[64*64];
    __shared__ u16 Bs[256*64];
    const int t = threadIdx.x, w = t >> 6;
    const int lane = t & 63, lo = lane & 15, hi = lane >> 4;
    const int bm = blockIdx.x * 64;
    f32x4 acc[16] = {};

    for (int k0 = 0; k0 < K; k0 += 64) {
        __syncthreads();
        #pragma unroll
        for (int i = 0; i < 2; ++i) {
            int id = i*256 + t;
            int row = id >> 3, c = id & 7, cs = c ^ (row & 7);
            gload_lds16(A + (size_t)(bm + row) * lda + k0 + cs*8,
                        &As[(i*256 + w*64)*8]);
        }
        #pragma unroll
        for (int i = 0; i < 8; ++i) {
            int id = i*256 + t;
            int row = id >> 3, c = id & 7, cs = c ^ (row & 7);
            gload_lds16(Wt + (size_t)row * K + k0 + cs*8,
                        &Bs[(i*256 + w*64)*8]);
        }
        __syncthreads();
        #pragma unroll
        for (int ks = 0; ks < 2; ++ks) {
            int arow = w*16 + lo;
            bf16x8 af = *(const bf16x8*)&As[arow*64 + (((ks*4 + hi) ^ (arow & 7)) * 8)];
            #pragma unroll
            for (int n = 0; n < 16; ++n) {
                int brow = n*16 + lo;
                bf16x8 bfr = *(const bf16x8*)&Bs[brow*64 + (((ks*4 + hi) ^ (brow & 7)) * 8)];
                acc[n] = __builtin_amdgcn_mfma_f32_16x16x32_bf16(af, bfr, acc[n], 0, 0, 0);
            }
        }
    }

    float bvv[16];
    #pragma unroll
    for (int n = 0; n < 16; ++n) bvv[n] = bias[n*16 + lo];

    float vv[4][16];
    float summ[4], sq[4];
    #pragma unroll
    for (int r = 0; r < 4; ++r) {
        int grow = bm + w*16 + hi*4 + r;
        float s_ = 0.f, q_ = 0.f;
        #pragma unroll
        for (int n = 0; n < 16; ++n) {
            float val = acc[n][r] + bvv[n] + X[(size_t)grow*256 + n*16 + lo];
            vv[r][n] = val;
            s_ += val; q_ += val*val;
        }
        #pragma unroll
        for (int n = 0; n < 16; ++n)
            X[(size_t)grow*256 + n*16 + lo] = vv[r][n];
        summ[r] = s_; sq[r] = q_;
    }
    if (LNOUT) {
        #pragma unroll
        for (int m = 1; m < 16; m <<= 1) {
            #pragma unroll
            for (int r = 0; r < 4; ++r) {
                summ[r] += __shfl_xor(summ[r], m);
                sq[r]   += __shfl_xor(sq[r], m);
            }
        }
        float lsv[16], lbv[16];
        #pragma unroll
        for (int n = 0; n < 16; ++n) { lsv[n] = ls[n*16+lo]; lbv[n] = lb[n*16+lo]; }
        #pragma unroll
        for (int r = 0; r < 4; ++r) {
            int grow = bm + w*16 + hi*4 + r;
            float mean = summ[r] * (1.f/256.f);
            float var  = sq[r] * (1.f/256.f) - mean*mean;
            float rstd = rsqrtf(var + 1e-5f);
            #pragma unroll
            for (int n = 0; n < 16; ++n) {
                float h = (vv[r][n] - mean)*rstd*lsv[n] + lbv[n];
                Hb[(size_t)grow*256 + n*16 + lo] = f2bf(h);
            }
        }
    }
}

// ---------------------------------------------------------------------------
// Softmax step (base-2 domain). See R7 notes.
// ---------------------------------------------------------------------------
template<bool MASK>
__device__ __forceinline__ void qk_softmax(
    f32x4 (&sacc)[4], float& mrow, float& lrow, f32x4 (&oacc)[4],
    unsigned* __restrict__ PW, int lo, int hi, int w)
{
    float p[4][4];
    float pmax = -1e30f;
    #pragma unroll
    for (int mf = 0; mf < 4; ++mf)
        #pragma unroll
        for (int r = 0; r < 4; ++r) {
            float s = sacc[mf][r];
            if (MASK) {
                int key = mf*16 + hi*4 + r;
                int q = w*16 + lo;
                if (key > q) s = -1e9f;
            }
            p[mf][r] = s;
            pmax = fmaxf(pmax, s);
        }
    pmax = fmaxf(pmax, __shfl_xor(pmax, 16));
    pmax = fmaxf(pmax, __shfl_xor(pmax, 32));
    if (!__all(pmax - mrow <= 11.5f)) {          // ~e^8 in base-2 domain
        float mnew = fmaxf(mrow, pmax);
        float alpha = __builtin_amdgcn_exp2f(mrow - mnew);
        mrow = mnew;
        lrow *= alpha;
        float al[4];
        #pragma unroll
        for (int r = 0; r < 4; ++r) al[r] = __shfl(alpha, hi*4 + r);
        #pragma unroll
        for (int n = 0; n < 4; ++n) {
            oacc[n][0] *= al[0]; oacc[n][1] *= al[1];
            oacc[n][2] *= al[2]; oacc[n][3] *= al[3];
        }
    }
    float rsum = 0.f;
    #pragma unroll
    for (int mf = 0; mf < 4; ++mf)
        #pragma unroll
        for (int r = 0; r < 4; ++r) {
            float e = __builtin_amdgcn_exp2f(p[mf][r] - mrow);
            p[mf][r] = e;
            rsum += e;
        }
    rsum += __shfl_xor(rsum, 16);
    rsum += __shfl_xor(rsum, 32);
    lrow += rsum;
    #pragma unroll
    for (int mf = 0; mf < 4; ++mf) {
        int c = mf*2 + (hi >> 1);
        int base2 = lo*32 + ((c ^ (lo & 7)) * 4) + (hi & 1) * 2;
        unsigned px, py;
        asm("v_cvt_pk_bf16_f32 %0, %1, %2" : "=v"(px) : "v"(p[mf][0]), "v"(p[mf][1]));
        asm("v_cvt_pk_bf16_f32 %0, %1, %2" : "=v"(py) : "v"(p[mf][2]), "v"(p[mf][3]));
        uint2 pk; pk.x = px; pk.y = py;
        *(uint2*)&PW[base2] = pk;
    }
}

// ---------------------------------------------------------------------------
// MFMA flash attention (R11 configuration — proven best).
// ---------------------------------------------------------------------------
__global__ __launch_bounds__(256, 4) void attn_mfma(
    const u16* __restrict__ QKV, const u16* __restrict__ Vt,
    u16* __restrict__ O)
{
    const int bid = blockIdx.x;
    const int bh = bid & 127;
    const int x  = bid >> 7;
    const int b  = bh >> 2, h = bh & 3;
    const int qta = x;
    const int qtb = 12 - x;
    const bool Bact = (x != 6);
    __shared__ u16 Kbuf[2][64*64];
    __shared__ u16 Vbuf[2][64*64];
    __shared__ u16 Plds[4][16*64];
    const int t = threadIdx.x, w = t >> 6;
    const int lane = t & 63, lo = lane & 15, hi = lane >> 4;

    bf16x8 qfA[2], qfB[2];
    {
        const u16* qp = QKV + ((size_t)(b*TT + qta*64 + w*16 + lo)) * 768 + h*64 + hi*8;
        qfA[0] = *(const bf16x8*)qp;
        qfA[1] = *(const bf16x8*)(qp + 32);
    }
    if (Bact) {
        const u16* qp = QKV + ((size_t)(b*TT + qtb*64 + w*16 + lo)) * 768 + h*64 + hi*8;
        qfB[0] = *(const bf16x8*)qp;
        qfB[1] = *(const bf16x8*)(qp + 32);
    }
    const u16* kB0 = QKV + ((size_t)b*TT) * 768 + 256 + h*64;
    const u16* vB0 = Vt + ((size_t)(b*NH + h) * 64) * TT;

    f32x4 oaccA[4] = {}, oaccB[4] = {};
    float mA = -1e30f, lA = 0.f, mB = -1e30f, lB = 0.f;
    unsigned* PW = (unsigned*)&Plds[w][0];
    const u16* Pw = &Plds[w][0];

    #define ATTN_STAGE(buf, kt) do { \
        _Pragma("unroll") \
        for (int i_ = 0; i_ < 2; ++i_) { \
            int id_ = i_*256 + t; \
            int row_ = id_ >> 3, c_ = id_ & 7, cs_ = c_ ^ (row_ & 7); \
            gload_lds16(kB0 + ((size_t)((kt)*64 + row_)) * 768 + cs_*8, \
                        &Kbuf[buf][(i_*256 + w*64)*8]); \
            gload_lds16(vB0 + (size_t)row_ * TT + (kt)*64 + cs_*8, \
                        &Vbuf[buf][(i_*256 + w*64)*8]); \
        } \
    } while (0)

    #define PV_TILE(Vc, oacc) do { \
        bf16x8 pf0 = *(const bf16x8*)&Pw[lo*64 + (((0 + hi) ^ (lo & 7)) * 8)]; \
        bf16x8 pf1 = *(const bf16x8*)&Pw[lo*64 + (((4 + hi) ^ (lo & 7)) * 8)]; \
        __builtin_amdgcn_s_setprio(1); \
        _Pragma("unroll") \
        for (int n_ = 0; n_ < 4; ++n_) { \
            int d_ = n_*16 + lo; \
            bf16x8 v0 = *(const bf16x8*)&Vc[d_*64 + (((0 + hi) ^ (d_ & 7)) * 8)]; \
            bf16x8 v1 = *(const bf16x8*)&Vc[d_*64 + (((4 + hi) ^ (d_ & 7)) * 8)]; \
            oacc[n_] = __builtin_amdgcn_mfma_f32_16x16x32_bf16(pf0, v0, oacc[n_], 0, 0, 0); \
            oacc[n_] = __builtin_amdgcn_mfma_f32_16x16x32_bf16(pf1, v1, oacc[n_], 0, 0, 0); \
        } \
        __builtin_amdgcn_s_setprio(0); \
    } while (0)

    const int ktmax = Bact ? qtb : qta;
    ATTN_STAGE(0, 0);
    int cur = 0;

    for (int kt = 0; kt <= ktmax; ++kt) {
        if (kt < ktmax) {
            ATTN_STAGE(cur ^ 1, kt + 1);      // 4 vm instrs, stay in flight
            __builtin_amdgcn_sched_barrier(0);
            asm volatile("s_waitcnt vmcnt(4)" ::: "memory");  // prev stage done
        } else {
            asm volatile("s_waitcnt vmcnt(0)" ::: "memory");
        }
        __builtin_amdgcn_s_barrier();          // cur tile visible to all waves
        __builtin_amdgcn_sched_barrier(0);
        const u16* Kc = &Kbuf[cur][0];
        const u16* Vc = &Vbuf[cur][0];
        const bool Aact = (kt <= qta);

        f32x4 saccA[4] = {}, saccB[4] = {};
        __builtin_amdgcn_s_setprio(1);
        #pragma unroll
        for (int mf = 0; mf < 4; ++mf) {
            int row = mf*16 + lo;
            bf16x8 k0 = *(const bf16x8*)&Kc[row*64 + (((0 + hi) ^ (row & 7)) * 8)];
            bf16x8 k1 = *(const bf16x8*)&Kc[row*64 + (((4 + hi) ^ (row & 7)) * 8)];
            if (Aact) {
                saccA[mf] = __builtin_amdgcn_mfma_f32_16x16x32_bf16(k0, qfA[0], saccA[mf], 0, 0, 0);
                saccA[mf] = __builtin_amdgcn_mfma_f32_16x16x32_bf16(k1, qfA[1], saccA[mf], 0, 0, 0);
            }
            if (Bact) {
                saccB[mf] = __builtin_amdgcn_mfma_f32_16x16x32_bf16(k0, qfB[0], saccB[mf], 0, 0, 0);
                saccB[mf] = __builtin_amdgcn_mfma_f32_16x16x32_bf16(k1, qfB[1], saccB[mf], 0, 0, 0);
            }
        }
        __builtin_amdgcn_s_setprio(0);

        if (Aact) {
            if (kt == qta) qk_softmax<true >(saccA, mA, lA, oaccA, PW, lo, hi, w);
            else           qk_softmax<false>(saccA, mA, lA, oaccA, PW, lo, hi, w);
            PV_TILE(Vc, oaccA);                // overlaps smB below (MFMA vs VALU)
        }
        if (Bact) {
            if (kt == qtb) qk_softmax<true >(saccB, mB, lB, oaccB, PW, lo, hi, w);
            else           qk_softmax<false>(saccB, mB, lB, oaccB, PW, lo, hi, w);
            PV_TILE(Vc, oaccB);
        }
        __builtin_amdgcn_sched_barrier(0);
        __builtin_amdgcn_s_barrier();          // all reads of cur done
        __builtin_amdgcn_sched_barrier(0);
        cur ^= 1;
    }
    #undef ATTN_STAGE
    #undef PV_TILE

    {
        float linv[4];
        #pragma unroll
        for (int r = 0; r < 4; ++r) linv[r] = 1.0f / __shfl(lA, hi*4 + r);
        #pragma unroll
        for (int n = 0; n < 4; ++n)
            #pragma unroll
            for (int r = 0; r < 4; ++r) {
                size_t row = (size_t)(b*TT + qta*64 + w*16 + hi*4 + r);
                O[row*256 + h*64 + n*16 + lo] = f2bf(oaccA[n][r] * linv[r]);
            }
    }
    if (Bact) {
        float linv[4];
        #pragma unroll
        for (int r = 0; r < 4; ++r) linv[r] = 1.0f / __shfl(lB, hi*4 + r);
        #pragma unroll
        for (int n = 0; n < 4; ++n)
            #pragma unroll
            for (int r = 0; r < 4; ++r) {
                size_t row = (size_t)(b*TT + qtb*64 + w*16 + hi*4 + r);
                O[row*256 + h*64 + n*16 + lo] = f2bf(oaccB[n][r] * linv[r]);
            }
    }
}

// ---------------------------------------------------------------------------
// fp32 GEMM (small matrices only). ACT: 0 none, 2 leaky
// ---------------------------------------------------------------------------
template<int ACT, bool RES>
__global__ __launch_bounds__(256) void gemm_f32(
    const float* __restrict__ A, const float* __restrict__ W,
    const float* __restrict__ bias, const float* __restrict__ Rsd,
    float* __restrict__ C, int M, int N, int K)
{
    __shared__ float As[16][68];
    __shared__ float Ws[16][68];
    const int bm = blockIdx.x * 64;
    const int bn = blockIdx.y * 64;
    const int t = threadIdx.x;
    const int tx = t & 15, ty = t >> 4;
    float c[4][4] = {};
    for (int k0 = 0; k0 < K; k0 += 16) {
        {
            int row = bm + (t >> 2);
            int kk = (t & 3) * 4;
            float4 a = make_float4(0.f, 0.f, 0.f, 0.f);
            if (row < M) a = *(const float4*)(A + (size_t)row * K + k0 + kk);
            int mm = t >> 2;
            As[kk+0][mm] = a.x; As[kk+1][mm] = a.y; As[kk+2][mm] = a.z; As[kk+3][mm] = a.w;
        }
        {
            int kr = t >> 4;
            int col = (t & 15) * 4;
            *(float4*)&Ws[kr][col] = *(const float4*)(W + (size_t)(k0 + kr) * N + bn + col);
        }
        __syncthreads();
        #pragma unroll
        for (int kk = 0; kk < 16; ++kk) {
            float4 a4 = *(const float4*)&As[kk][ty*4];
            float4 b4 = *(const float4*)&Ws[kk][tx*4];
            float av[4] = {a4.x, a4.y, a4.z, a4.w};
            float bb[4] = {b4.x, b4.y, b4.z, b4.w};
            #pragma unroll
            for (int i = 0; i < 4; ++i)
                #pragma unroll
                for (int j = 0; j < 4; ++j)
                    c[i][j] = fmaf(av[i], bb[j], c[i][j]);
        }
        __syncthreads();
    }
    float4 b4 = *(const float4*)(bias + bn + tx*4);
    float bvals[4] = {b4.x, b4.y, b4.z, b4.w};
    #pragma unroll
    for (int i = 0; i < 4; ++i) {
        int row = bm + ty*4 + i;
        if (row >= M) continue;
        float tmp[4];
        #pragma unroll
        for (int j = 0; j < 4; ++j) {
            float v = c[i][j] + bvals[j];
            if (ACT == 2) v = (v > 0.f) ? v : 0.01f * v;
            tmp[j] = v;
        }
        size_t off = (size_t)row * N + bn + tx*4;
        if (RES) {
            float4 r4 = *(const float4*)(Rsd + off);
            tmp[0] += r4.x; tmp[1] += r4.y; tmp[2] += r4.z; tmp[3] += r4.w;
        }
        *(float4*)(C + off) = make_float4(tmp[0], tmp[1], tmp[2], tmp[3]);
    }
}

// ---------------------------------------------------------------------------
// LayerNorm: fp32 in, bf16 out (used once, layer-0 ln1)
// ---------------------------------------------------------------------------
template<int OUTBF>
__global__ __launch_bounds__(256) void ln_kernel(const float* __restrict__ Xin,
    const float* __restrict__ sc, const float* __restrict__ bi,
    void* __restrict__ Y, int M)
{
    int row = blockIdx.x * 4 + (threadIdx.x >> 6);
    if (row >= M) return;
    int lane = threadIdx.x & 63;
    float4 xv = *(const float4*)(Xin + (size_t)row * DD + lane*4);
    float sum = xv.x + xv.y + xv.z + xv.w;
    float sq  = xv.x*xv.x + xv.y*xv.y + xv.z*xv.z + xv.w*xv.w;
    #pragma unroll
    for (int m = 32; m; m >>= 1) { sum += __shfl_xor(sum, m); sq += __shfl_xor(sq, m); }
    float mean = sum * (1.f/256.f);
    float var  = sq * (1.f/256.f) - mean*mean;
    float rs = rsqrtf(var + 1e-5f);
    float4 sv = *(const float4*)(sc + lane*4);
    float4 bv = *(const float4*)(bi + lane*4);
    float4 y;
    y.x = (xv.x - mean)*rs*sv.x + bv.x;
    y.y = (xv.y - mean)*rs*sv.y + bv.y;
    y.z = (xv.z - mean)*rs*sv.z + bv.z;
    y.w = (xv.w - mean)*rs*sv.w + bv.w;
    if (OUTBF) {
        ushort4 o; o.x = f2bf(y.x); o.y = f2bf(y.y); o.z = f2bf(y.z); o.w = f2bf(y.w);
        *(ushort4*)((u16*)Y + (size_t)row * DD + lane*4) = o;
    } else {
        *(float4*)((float*)Y + (size_t)row * DD + lane*4) = y;
    }
}

// ---------------------------------------------------------------------------
// Gather last-layer head rows: OG (bf16) = Ob[H_IDX], XG (fp32) = X[H_IDX]
// ---------------------------------------------------------------------------
__global__ __launch_bounds__(256) void gather_last(const u16* __restrict__ Ob,
    const float* __restrict__ X, u16* __restrict__ OG, float* __restrict__ XG)
{
    int idx = blockIdx.x * 256 + threadIdx.x;      // BB*NHID*64 = 131072
    int row = idx >> 6, c4 = (idx & 63) * 4;
    int b = row >> 6, i = row & 63;
    int tt = i*13 + 12;
    size_t src = ((size_t)(b*TT + tt)) * DD + c4;
    *(ushort4*)(OG + (size_t)row*DD + c4) = *(const ushort4*)(Ob + src);
    *(float4*)(XG + (size_t)row*DD + c4)  = *(const float4*)(X + src);
}

// ---------------------------------------------------------------------------
__global__ __launch_bounds__(256) void manual_pool(
    const float* __restrict__ em, const float* __restrict__ mk_w, const float* __restrict__ mk_b,
    const float* __restrict__ mv_w, const float* __restrict__ mv_b,
    float* __restrict__ MK, float* __restrict__ MV)
{
    int bs = blockIdx.x;
    const float* base = em + (size_t)bs * LMM * DD;
    __shared__ float ems[LMM][DD];
    __shared__ float wk_s[DD], wv_s[DD];
    __shared__ float sk[LMM], sv[LMM];
    __shared__ float inv2[2];
    int t = threadIdx.x;
    for (int i = t; i < LMM*DD/4; i += 256)
        ((float4*)&ems[0][0])[i] = ((const float4*)base)[i];
    wk_s[t] = mk_w[t];
    wv_s[t] = mv_w[t];
    __syncthreads();
    if (t < LMM) {
        float dk = 0.f, dv = 0.f;
        for (int d = 0; d < DD; ++d) {
            float e = ems[t][d];
            dk = fmaf(e, wk_s[d], dk);
            dv = fmaf(e, wv_s[d], dv);
        }
        sk[t] = dk + mk_b[0];
        sv[t] = dv + mv_b[0];
    }
    __syncthreads();
    if (t == 0) {
        float mk_ = -1e30f, mv_ = -1e30f;
        for (int l = 0; l < LMM; ++l) { mk_ = fmaxf(mk_, sk[l]); mv_ = fmaxf(mv_, sv[l]); }
        float sks = 0.f, svs = 0.f;
        for (int l = 0; l < LMM; ++l) {
            float ek = expf(sk[l]-mk_); sk[l] = ek; sks += ek;
            float ev = expf(sv[l]-mv_); sv[l] = ev; svs += ev;
        }
        inv2[0] = 1.f/sks; inv2[1] = 1.f/svs;
    }
    __syncthreads();
    float ak = 0.f, avv = 0.f;
    for (int l = 0; l < LMM; ++l) {
        float e = ems[l][t];
        ak  = fmaf(sk[l], e, ak);
        avv = fmaf(sv[l], e, avv);
    }
    MK[(size_t)bs*DD + t] = ak  * inv2[0];
    MV[(size_t)bs*DD + t] = avv * inv2[1];
}

__device__ __forceinline__ int qidx_to_t(int qi) {
    int blk = qi / 3, r = qi - blk*3;
    return blk*13 + (r == 0 ? 1 : (r == 1 ? 4 : 7));
}

__global__ void embed_kernel(const int* __restrict__ tokens,
    const float* __restrict__ emb_a, const float* __restrict__ emb_o,
    const float* __restrict__ pos, float* __restrict__ X)
{
    int idx = blockIdx.x * 256 + threadIdx.x;
    if (idx >= BT * 64) return;
    int row = idx >> 6;
    int c4 = (idx & 63) * 4;
    int tt = row % TT;
    int tok = tokens[row];
    const float* src = (tt % 13 == 0) ? (emb_a + tok * DD) : (emb_o + (size_t)tok * DD);
    float4 e = *(const float4*)(src + c4);
    float4 p = *(const float4*)(pos + (size_t)tt * DD + c4);
    *(float4*)(X + (size_t)row * DD + c4) = make_float4(e.x+p.x, e.y+p.y, e.z+p.z, e.w+p.w);
}

// Q positions are never action positions -> embeds[Q_IDX] = emb_obs[tokens]; bf16 out
__global__ void gather_q_kernel(const int* __restrict__ tokens,
    const float* __restrict__ emb_o, u16* __restrict__ Qin)
{
    int idx = blockIdx.x * 256 + threadIdx.x;
    if (idx >= BB * NQ * 64) return;
    int row = idx >> 6, c4 = (idx & 63) * 4;
    int b = row / NQ, qi = row - b*NQ;
    int tt = qidx_to_t(qi);
    int tok = tokens[b*TT + tt];
    float4 e = *(const float4*)(emb_o + (size_t)tok*DD + c4);
    ushort4 o; o.x = f2bf(e.x); o.y = f2bf(e.y); o.z = f2bf(e.z); o.w = f2bf(e.w);
    *(ushort4*)(Qin + (size_t)row*DD + c4) = o;
}

__global__ void scatter_av_kernel(const float* __restrict__ AVp, float* __restrict__ X)
{
    int idx = blockIdx.x * 256 + threadIdx.x;
    if (idx >= BB * NQ * 64) return;
    int row = idx >> 6, c4 = (idx & 63)*4;
    int b = row / NQ, qi = row - b*NQ;
    int tt = qidx_to_t(qi);
    float* xp = X + ((size_t)b*TT + tt)*DD + c4;
    float4 a = *(const float4*)(AVp + (size_t)row*DD + c4);
    float4 xv = *(const float4*)xp;
    *(float4*)xp = make_float4(xv.x+a.x, xv.y+a.y, xv.z+a.z, xv.w+a.w);
}

// 3-slot cross attention; Qm bf16, K/V fp32, AV bf16
__global__ __launch_bounds__(256) void manual_attn(
    const u16* __restrict__ Qm, const float* __restrict__ Kp,
    const float* __restrict__ Vp, u16* __restrict__ AV)
{
    int row = blockIdx.x * 4 + (threadIdx.x >> 6);
    int lane = threadIdx.x & 63;
    int b = row / NQ;
    ushort4 qv = *(const ushort4*)(Qm + (size_t)row * DD + lane*4);
    float qx = bf2f(qv.x), qy = bf2f(qv.y), qz = bf2f(qv.z), qw = bf2f(qv.w);
    float s[3];
    #pragma unroll
    for (int j = 0; j < 3; ++j) {
        float4 kv = *(const float4*)(Kp + ((size_t)b*SS + j)*DD + lane*4);
        float d = qx*kv.x + qy*kv.y + qz*kv.z + qw*kv.w;
        #pragma unroll
        for (int m = 32; m; m >>= 1) d += __shfl_xor(d, m);
        s[j] = d * 0.0625f;
    }
    float mx = fmaxf(s[0], fmaxf(s[1], s[2]));
    float p0 = expf(s[0]-mx), p1 = expf(s[1]-mx), p2 = expf(s[2]-mx);
    float inv = 1.f/(p0+p1+p2);
    p0 *= inv; p1 *= inv; p2 *= inv;
    float4 v0 = *(const float4*)(Vp + ((size_t)b*SS+0)*DD + lane*4);
    float4 v1 = *(const float4*)(Vp + ((size_t)b*SS+1)*DD + lane*4);
    float4 v2 = *(const float4*)(Vp + ((size_t)b*SS+2)*DD + lane*4);
    ushort4 o;
    o.x = f2bf(p0*v0.x + p1*v1.x + p2*v2.x);
    o.y = f2bf(p0*v0.y + p1*v1.y + p2*v2.y);
    o.z = f2bf(p0*v0.z + p1*v1.z + p2*v2.z);
    o.w = f2bf(p0*v0.w + p1*v1.w + p2*v2.w);
    *(ushort4*)(AV + (size_t)row * DD + lane*4) = o;
}

// final head matmuls + softmax; A2/V2 bf16
__global__ __launch_bounds__(64) void head_final(
    const u16* __restrict__ A2, const float* __restrict__ w3a, const float* __restrict__ b3a,
    const u16* __restrict__ V2, const float* __restrict__ w3v, const float* __restrict__ b3v,
    float* __restrict__ out)
{
    int row = blockIdx.x;
    int lane = threadIdx.x;
    ushort4 av = *(const ushort4*)(A2 + (size_t)row*DD + lane*4);
    float a0 = bf2f(av.x), a1 = bf2f(av.y), a2 = bf2f(av.z), a3 = bf2f(av.w);
    float lg[5];
    #pragma unroll
    for (int j = 0; j < 5; ++j) {
        float p = a0*w3a[(lane*4+0)*5+j] + a1*w3a[(lane*4+1)*5+j]
                + a2*w3a[(lane*4+2)*5+j] + a3*w3a[(lane*4+3)*5+j];
        #pragma unroll
        for (int m = 32; m; m >>= 1) p += __shfl_xor(p, m);
        lg[j] = p + b3a[j];
    }
    ushort4 vv = *(const ushort4*)(V2 + (size_t)row*DD + lane*4);
    float pv = bf2f(vv.x)*w3v[lane*4+0] + bf2f(vv.y)*w3v[lane*4+1]
             + bf2f(vv.z)*w3v[lane*4+2] + bf2f(vv.w)*w3v[lane*4+3];
    #pragma unroll
    for (int m = 32; m; m >>= 1) pv += __shfl_xor(pv, m);
    if (lane == 0) {
        float mx = lg[0];
        #pragma unroll
        for (int j = 1; j < 5; ++j) mx = fmaxf(mx, lg[j]);
        float e[5], ssum = 0.f;
        #pragma unroll
        for (int j = 0; j < 5; ++j) { e[j] = expf(lg[j]-mx); ssum += e[j]; }
        float inv = 1.f/ssum;
        #pragma unroll
        for (int j = 0; j < 5; ++j) out[(size_t)row*5 + j] = e[j]*inv;
        out[(size_t)BB*NHID*5 + row] = pv + b3v[0];
    }
}

// ---------------------------------------------------------------------------
extern "C" void kernel_launch(void* const* d_in, const int* in_sizes, int n_in,
                              void* d_out, int out_size, void* d_ws, size_t ws_size,
                              hipStream_t stream)
{
    (void)in_sizes; (void)n_in; (void)out_size; (void)ws_size;
    const int*   tokens = (const int*)d_in[0];
    const float* em     = (const float*)d_in[1];
    const float* emb_a  = (const float*)d_in[2];
    const float* emb_o  = (const float*)d_in[3];
    const float* pos    = (const float*)d_in[4];
    const float* mk_w   = (const float*)d_in[5];
    const float* mk_b   = (const float*)d_in[6];
    const float* mv_w   = (const float*)d_in[7];
    const float* mv_b   = (const float*)d_in[8];
    const float* ma_wq  = (const float*)d_in[9];
    const float* ma_bq  = (const float*)d_in[10];
    const float* ma_wk  = (const float*)d_in[11];
    const float* ma_bk  = (const float*)d_in[12];
    const float* ma_wv  = (const float*)d_in[13];
    const float* ma_bv  = (const float*)d_in[14];
    const float* ma_wo  = (const float*)d_in[15];
    const float* ma_bo  = (const float*)d_in[16];
    const float* ln1_s  = (const float*)d_in[17];
    const float* ln1_b  = (const float*)d_in[18];
    const float* wq     = (const float*)d_in[19];
    const float* bq     = (const float*)d_in[20];
    const float* wk     = (const float*)d_in[21];
    const float* bk     = (const float*)d_in[22];
    const float* wv     = (const float*)d_in[23];
    const float* bv     = (const float*)d_in[24];
    const float* wo     = (const float*)d_in[25];
    const float* bo     = (const float*)d_in[26];
    const float* ln2_s  = (const float*)d_in[27];
    const float* ln2_b  = (const float*)d_in[28];
    const float* w1     = (const float*)d_in[29];
    const float* b1     = (const float*)d_in[30];
    const float* w2     = (const float*)d_in[31];
    const float* b2     = (const float*)d_in[32];
    const float* lnf_s  = (const float*)d_in[33];
    const float* lnf_b  = (const float*)d_in[34];
    const float* ha_w1  = (const float*)d_in[35];
    const float* ha_b1  = (const float*)d_in[36];
    const float* ha_w2  = (const float*)d_in[37];
    const float* ha_b2  = (const float*)d_in[38];
    const float* ha_w3  = (const float*)d_in[39];
    const float* ha_b3  = (const float*)d_in[40];
    const float* hv_w1  = (const float*)d_in[41];
    const float* hv_b1  = (const float*)d_in[42];
    const float* hv_w2  = (const float*)d_in[43];
    const float* hv_b2  = (const float*)d_in[44];
    const float* hv_w3  = (const float*)d_in[45];
    const float* hv_b3  = (const float*)d_in[46];

    char* base = (char*)d_ws;
    const size_t OFF_X    = 0;
    const size_t OFF_HB   = 27262976;   // X: BT*256*4
    const size_t OFF_QKV  = 40894464;   // Hb: BT*256*2
    const size_t OFF_VT   = 81788928;   // QKV: BT*768*2
    const size_t OFF_OB   = 95420416;   // Vt: 32*4*64*832*2
    const size_t OFF_MID  = 109051904;  // Ob: BT*256*2
    const size_t OFF_W    = 163577856;  // MID: BT*1024*2

    float* X    = (float*)(base + OFF_X);
    u16*   Hb   = (u16*)(base + OFF_HB);
    u16*   QKVb = (u16*)(base + OFF_QKV);
    u16*   Vt   = (u16*)(base + OFF_VT);
    u16*   Ob   = (u16*)(base + OFF_OB);
    u16*   MID  = (u16*)(base + OFF_MID);
    u16*   Wqkv = (u16*)(base + OFF_W);                 // [NL][768][256]
    u16*   Wo   = Wqkv + (size_t)NLAYER*768*256;        // [NL][256][256]
    u16*   W1t  = Wo   + (size_t)NLAYER*256*256;        // [NL][1024][256]
    u16*   W2t  = W1t  + (size_t)NLAYER*1024*256;       // [NL][256][1024]
    float* bqkv = (float*)(W2t + (size_t)NLAYER*256*1024);  // [NL][768]
    u16*   Wmq  = (u16*)(bqkv + NLAYER*768);            // [256][256]
    u16*   Wmo  = Wmq  + 256*256;
    u16*   Wha1 = Wmo  + 256*256;
    u16*   Wha2 = Wha1 + 256*256;
    u16*   Whv1 = Wha2 + 256*256;
    u16*   Whv2 = Whv1 + 256*256;

    // aliases into regions dead during pre/post stages:
    u16*   MQIN = (u16*)(base + OFF_MID);
    u16*   MQ   = MQIN + (size_t)BB*NQ*DD;
    u16*   MAV  = MQ   + (size_t)BB*NQ*DD;
    float* MAVP = (float*)(MAV + (size_t)BB*NQ*DD);
    float* MKp  = (float*)(base + OFF_VT);
    float* MVp  = MKp + BB*SS*DD;
    float* KP   = MVp + BB*SS*DD;
    float* VP   = KP  + BB*SS*DD;
    u16*   HXNb = (u16*)(base + OFF_MID);               // post-stage (MID dead)
    u16*   A1b  = HXNb + (size_t)BB*NHID*DD;
    u16*   A2b  = A1b  + (size_t)BB*NHID*DD;
    u16*   V1b  = A2b  + (size_t)BB*NHID*DD;
    u16*   V2b  = V1b  + (size_t)BB*NHID*DD;
    // last-layer gathered buffers (further into dead MID region):
    u16*   OG   = V2b  + (size_t)BB*NHID*DD;            // [2048][256] bf16
    float* XG   = (float*)(OG + (size_t)BB*NHID*DD);    // [2048][256] fp32
    u16*   HbG  = (u16*)(XG + (size_t)BB*NHID*DD);      // [2048][256] bf16
    u16*   MIDG = HbG + (size_t)BB*NHID*DD;             // [2048][1024] bf16

    // ---- weight conversion (single launch) ----
    wtrans_all<<<3468, 256, 0, stream>>>(wq, wk, wv, wo, w1, w2, ma_wq, ma_wo,
                                         ha_w1, ha_w2, hv_w1, hv_w2,
                                         bq, bk, bv,
                                         Wqkv, Wo, W1t, W2t, Wmq, Wmo,
                                         Wha1, Wha2, Whv1, Whv2, bqkv);

    #define GEMMF(ACT, RES, A_, W_, BIAS_, R_, C_, M_, N_, K_) \
        gemm_f32<ACT, RES><<<dim3(((M_)+63)/64, (N_)/64), 256, 0, stream>>>(A_, W_, BIAS_, R_, C_, M_, N_, K_)

    // ---- pre-stage ----
    manual_pool<<<BB*SS, 256, 0, stream>>>(em, mk_w, mk_b, mv_w, mv_b, MKp, MVp);
    embed_kernel<<<(BT*64)/256, 256, 0, stream>>>(tokens, emb_a, emb_o, pos, X);
    gather_q_kernel<<<(BB*NQ*64)/256, 256, 0, stream>>>(tokens, emb_o, MQIN);
    gemm_bf16<0,0,1,0,0,4><<<96, 256, 0, stream>>>(
        MQIN, 256, Wmq, ma_bq, (const float*)nullptr, MQ, 256, 256, (u16*)nullptr, 48);
    GEMMF(0, false, MKp,  ma_wk, ma_bk, (const float*)nullptr, KP, BB*SS, DD, DD);
    GEMMF(0, false, MVp,  ma_wv, ma_bv, (const float*)nullptr, VP, BB*SS, DD, DD);
    manual_attn<<<(BB*NQ)/4, 256, 0, stream>>>(MQ, KP, VP, MAV);
    gemm_bf16<0,0,0,0,0,4><<<96, 256, 0, stream>>>(
        MAV, 256, Wmo, ma_bo, (const float*)nullptr, MAVP, 256, 256, (u16*)nullptr, 48);
    scatter_av_kernel<<<(BB*NQ*64)/256, 256, 0, stream>>>(MAVP, X);

    // ---- transformer layers (bf16 MFMA; LN fused into residual GEMMs) ----
    ln_kernel<1><<<BT/4, 256, 0, stream>>>(X, ln1_s, ln1_b, Hb, BT);  // layer-0 ln1
    for (int l = 0; l < NLAYER; ++l) {
        gemm_bf16<0,0,1,1,1,4><<<1248, 256, 0, stream>>>(
            Hb, 256, Wqkv + (size_t)l*768*256, bqkv + l*768,
            (const float*)nullptr, QKVb, 768, 256, Vt, 208);
        attn_mfma<<<896, 256, 0, stream>>>(QKVb, Vt, Ob);
        if (l < NLAYER-1) {
            gemm_res_ln<1><<<416, 256, 0, stream>>>(
                Ob, 256, Wo + (size_t)l*256*256, bo + l*DD, X,
                ln2_s + l*DD, ln2_b + l*DD, Hb, 256);
            gemm_bf16<1,0,1,0,0,4><<<1664, 256, 0, stream>>>(
                Hb, 256, W1t + (size_t)l*1024*256, b1 + l*FF,
                (const float*)nullptr, MID, 1024, 256, (u16*)nullptr, 208);
            gemm_res_ln<1><<<416, 256, 0, stream>>>(
                MID, 1024, W2t + (size_t)l*256*1024, b2 + l*DD, X,
                ln1_s + (l+1)*DD, ln1_b + (l+1)*DD, Hb, 1024);
        } else {
            // Last layer: only H_IDX rows (t%13==12) are consumed downstream.
            gather_last<<<(BB*NHID*64)/256, 256, 0, stream>>>(Ob, X, OG, XG);
            gemm_res_ln<1><<<(BB*NHID)/64, 256, 0, stream>>>(
                OG, 256, Wo + (size_t)l*256*256, bo + l*DD, XG,
                ln2_s + l*DD, ln2_b + l*DD, HbG, 256);
            gemm_bf16<1,0,1,0,0,4><<<128, 256, 0, stream>>>(
                HbG, 256, W1t + (size_t)l*1024*256, b1 + l*FF,
                (const float*)nullptr, MIDG, 1024, 256, (u16*)nullptr, 16);
            gemm_res_ln<1><<<(BB*NHID)/64, 256, 0, stream>>>(
                MIDG, 1024, W2t + (size_t)l*256*1024, b2 + l*DD, XG,
                lnf_s, lnf_b, HXNb, 1024);
        }
    }

    // ---- post-stage (bf16 MFMA heads; HXNb already holds lnf output) ----
    gemm_bf16<2,0,1,0,0,4><<<32, 256, 0, stream>>>(
        HXNb, 256, Wha1, ha_b1, (const float*)nullptr, A1b, 256, 256, (u16*)nullptr, 16);
    gemm_bf16<2,0,1,0,0,4><<<32, 256, 0, stream>>>(
        A1b, 256, Wha2, ha_b2, (const float*)nullptr, A2b, 256, 256, (u16*)nullptr, 16);
    gemm_bf16<2,0,1,0,0,4><<<32, 256, 0, stream>>>(
        HXNb, 256, Whv1, hv_b1, (const float*)nullptr, V1b, 256, 256, (u16*)nullptr, 16);
    gemm_bf16<2,0,1,0,0,4><<<32, 256, 0, stream>>>(
        V1b, 256, Whv2, hv_b2, (const float*)nullptr, V2b, 256, 256, (u16*)nullptr, 16);
    head_final<<<BB*NHID, 64, 0, stream>>>(A2b, ha_w3, ha_b3, V2b, hv_w3, hv_b3, (float*)d_out);
    #undef GEMMF
}

// Round 17
// 755.401 us; speedup vs baseline: 1.1159x; 1.1159x over previous
//
#include <hip/hip_runtime.h>
#include <math.h>

#define BB 32
#define TT 832
#define DD 256
#define NLAYER 4
#define NH 4
#define HDIM 64
#define FF 1024
#define SS 3
#define LMM 36
#define BT (BB*TT)      // 26624
#define NQ 192
#define NHID 64

typedef unsigned short u16;
typedef __attribute__((ext_vector_type(8))) short bf16x8;   // 8 bf16 (4 VGPR)
typedef __attribute__((ext_vector_type(4))) float f32x4;    // 4 fp32

// Hardware bf16 convert (RNE). 1 VALU op.
__device__ __forceinline__ u16 f2bf(float f) {
    unsigned r;
    asm("v_cvt_pk_bf16_f32 %0, %1, %1" : "=v"(r) : "v"(f));
    return (u16)r;
}
__device__ __forceinline__ float bf2f(u16 b) {
    return __builtin_bit_cast(float, (unsigned)b << 16);
}

__device__ __forceinline__ void gload_lds16(const void* g, void* l) {
    __builtin_amdgcn_global_load_lds(
        (const __attribute__((address_space(1))) unsigned int*)g,
        (__attribute__((address_space(3))) unsigned int*)l, 16, 0, 0);
}

static __device__ __forceinline__ float gelu_tanh(float x) {
    float z = 0.7978845608028654f * (x + 0.044715f * x * x * x);
    float t = 1.f - 2.f / (1.f + __expf(2.f * z));
    return 0.5f * x * (1.f + t);
}

// ---------------------------------------------------------------------------
// Merged weight convert+transpose + bias concat. One launch, 3468 blocks.
// ---------------------------------------------------------------------------
__global__ __launch_bounds__(256) void wtrans_all(
    const float* __restrict__ wq, const float* __restrict__ wk,
    const float* __restrict__ wv, const float* __restrict__ wo,
    const float* __restrict__ w1, const float* __restrict__ w2,
    const float* __restrict__ ma_wq, const float* __restrict__ ma_wo,
    const float* __restrict__ ha_w1, const float* __restrict__ ha_w2,
    const float* __restrict__ hv_w1, const float* __restrict__ hv_w2,
    const float* __restrict__ bq, const float* __restrict__ bk,
    const float* __restrict__ bv,
    u16* __restrict__ Wqkv, u16* __restrict__ Wo_, u16* __restrict__ W1t,
    u16* __restrict__ W2t, u16* __restrict__ Wmq, u16* __restrict__ Wmo,
    u16* __restrict__ Wha1, u16* __restrict__ Wha2,
    u16* __restrict__ Whv1, u16* __restrict__ Whv2,
    float* __restrict__ bqkv)
{
    __shared__ float tile[32][33];
    int bid = blockIdx.x;
    int t = threadIdx.x;
    if (bid >= 3456) {
        int i = (bid - 3456) * 256 + t;       // [0, NL*768)
        int l = i / 768, j = i - l * 768;
        float v = (j < 256) ? bq[l*256 + j]
                : (j < 512) ? bk[l*256 + j - 256]
                            : bv[l*256 + j - 512];
        bqkv[i] = v;
        return;
    }
    const float* src; u16* dst; int K, N, row0, nrows, bx, by, l;
    if (bid < 1024) {
        int job = bid >> 8, local = bid & 255;
        bx = local & 7; by = (local >> 3) & 7; l = local >> 6;
        K = 256; N = 256;
        nrows = (job < 3) ? 768 : 256;
        row0  = (job < 3) ? job * 256 : 0;
        src = (job == 0) ? wq : (job == 1) ? wk : (job == 2) ? wv : wo;
        dst = (job < 3) ? Wqkv : Wo_;
    } else if (bid < 2048) {
        int local = bid - 1024;
        bx = local & 31; by = (local >> 5) & 7; l = local >> 8;
        K = 256; N = 1024; row0 = 0; nrows = 1024; src = w1; dst = W1t;
    } else if (bid < 3072) {
        int local = bid - 2048;
        bx = local & 7; by = (local >> 3) & 31; l = local >> 8;
        K = 1024; N = 256; row0 = 0; nrows = 256; src = w2; dst = W2t;
    } else {
        int local = bid - 3072;               // 0..383
        int which = local >> 6;               // 0..5
        int loc2 = local & 63;
        bx = loc2 & 7; by = loc2 >> 3; l = 0;
        K = 256; N = 256; row0 = 0; nrows = 256;
        const float* srcs[6] = {ma_wq, ma_wo, ha_w1, ha_w2, hv_w1, hv_w2};
        u16* dsts[6] = {Wmq, Wmo, Wha1, Wha2, Whv1, Whv2};
        src = srcs[which];
        dst = dsts[which];
    }
    int n0 = bx * 32, k0 = by * 32;
    const float* s = src + (size_t)l * K * N;
    u16* d = dst + (size_t)l * nrows * K;
    int r = t >> 3, c4 = (t & 7) * 4;
    float4 v = *(const float4*)(s + (size_t)(k0 + r) * N + n0 + c4);
    tile[r][c4+0] = v.x; tile[r][c4+1] = v.y; tile[r][c4+2] = v.z; tile[r][c4+3] = v.w;
    __syncthreads();
    int nr = t >> 3, kc4 = (t & 7) * 4;
    ushort4 o;
    o.x = f2bf(tile[kc4+0][nr]); o.y = f2bf(tile[kc4+1][nr]);
    o.z = f2bf(tile[kc4+2][nr]); o.w = f2bf(tile[kc4+3][nr]);
    *(ushort4*)(d + (size_t)(row0 + n0 + nr) * K + k0 + kc4) = o;
}

// ---------------------------------------------------------------------------
// bf16 MFMA GEMM: C[M,N] = act(A[M,K]@W + bias) (+res). Wt is [N][K] bf16.
// BM=128, BN=NF*32, BK=64, 4 waves (2x2), 16x16x32 mfma, swizzled LDS,
// XCD swizzle over 1-D grid (nbx%8==0). SCALEQ: cols [0,256) * 0.125*log2e.
// VOUT (NF=4 only): bnb>=4 writes V transposed into Vt.
// ---------------------------------------------------------------------------
template<int ACT, int RES, int OUTBF, int SCALEQ, int VOUT, int NF>
__global__ __launch_bounds__(256) void gemm_bf16(
    const u16* __restrict__ A, int lda,
    const u16* __restrict__ Wt,
    const float* __restrict__ bias,
    const float* __restrict__ Rsd,
    void* __restrict__ Cout, int ldc, int K,
    u16* __restrict__ Vtout, int nbx)
{
    constexpr int BN = NF * 32;
    __shared__ u16 SMEM[128*64 + BN*64];
    u16* As = SMEM;
    u16* Bs = SMEM + 128*64;
    const int t = threadIdx.x, w = t >> 6;
    const int lane = t & 63, lo = lane & 15, hi = lane >> 4;
    const int kblk = blockIdx.x;
    const int xcd = kblk & 7;
    const int j = kblk >> 3;
    const int chunk = nbx >> 3;
    const int bmb = xcd * chunk + j % chunk;
    const int bnb = j / chunk;
    const int bm = bmb * 128, bn = bnb * BN;
    const int wr = w >> 1, wc = w & 1;
    f32x4 acc[4][NF] = {};

    for (int k0 = 0; k0 < K; k0 += 64) {
        __syncthreads();
        #pragma unroll
        for (int i = 0; i < 4; ++i) {
            int id = i*256 + t;
            int row = id >> 3, c = id & 7, cs = c ^ (row & 7);
            gload_lds16(A + (size_t)(bm + row) * lda + k0 + cs*8,
                        &As[(i*256 + w*64)*8]);
        }
        #pragma unroll
        for (int i = 0; i < BN/32; ++i) {
            int id = i*256 + t;
            int row = id >> 3, c = id & 7, cs = c ^ (row & 7);
            gload_lds16(Wt + (size_t)(bn + row) * K + k0 + cs*8,
                        &Bs[(i*256 + w*64)*8]);
        }
        __syncthreads();
        #pragma unroll
        for (int ks = 0; ks < 2; ++ks) {
            bf16x8 af[4], bfr[NF];
            #pragma unroll
            for (int m = 0; m < 4; ++m) {
                int row = wr*64 + m*16 + lo;
                af[m] = *(const bf16x8*)&As[row*64 + (((ks*4 + hi) ^ (row & 7)) * 8)];
            }
            #pragma unroll
            for (int n = 0; n < NF; ++n) {
                int row = wc*(NF*16) + n*16 + lo;
                bfr[n] = *(const bf16x8*)&Bs[row*64 + (((ks*4 + hi) ^ (row & 7)) * 8)];
            }
            #pragma unroll
            for (int m = 0; m < 4; ++m)
                #pragma unroll
                for (int n = 0; n < NF; ++n)
                    acc[m][n] = __builtin_amdgcn_mfma_f32_16x16x32_bf16(
                        af[m], bfr[n], acc[m][n], 0, 0, 0);
        }
    }
    float bv[NF];
    #pragma unroll
    for (int n = 0; n < NF; ++n) bv[n] = bias[bn + wc*(NF*16) + n*16 + lo];

    if constexpr (VOUT) {
        if (bnb >= 4) {
            // V columns: transpose through LDS, write Vt[b][h][d][t] directly.
            __syncthreads();             // done reading As/Bs
            u16* Vs = SMEM;              // [128 rows][128 cols]  (NF=4 only)
            #pragma unroll
            for (int m = 0; m < 4; ++m)
                #pragma unroll
                for (int r = 0; r < 4; ++r) {
                    int rowl = wr*64 + m*16 + hi*4 + r;
                    #pragma unroll
                    for (int n = 0; n < NF; ++n) {
                        int coll = wc*64 + n*16 + lo;
                        Vs[rowl*128 + coll] = f2bf(acc[m][n][r] + bv[n]);
                    }
                }
            __syncthreads();
            int c = t & 127;
            int g0 = (t >> 7) * 8;
            int hh = (bnb - 4) * 2 + (c >> 6);
            int dd = c & 63;
            #pragma unroll
            for (int g = g0; g < g0 + 8; ++g) {
                int tg = bm + g*8;           // 8-token group, single batch (832%8==0)
                int bb = tg / TT;
                int tloc = tg - bb*TT;
                u16 tmp[8];
                #pragma unroll
                for (int jj = 0; jj < 8; ++jj) tmp[jj] = Vs[(g*8 + jj)*128 + c];
                *(uint4*)(Vtout + ((size_t)((bb*NH + hh)*64 + dd)) * TT + tloc) =
                    *(uint4*)&tmp[0];
            }
            return;
        }
    }

    #pragma unroll
    for (int m = 0; m < 4; ++m) {
        #pragma unroll
        for (int r = 0; r < 4; ++r) {
            int grow = bm + wr*64 + m*16 + hi*4 + r;
            #pragma unroll
            for (int n = 0; n < NF; ++n) {
                int gcol = bn + wc*(NF*16) + n*16 + lo;
                float v = acc[m][n][r] + bv[n];
                if (ACT == 1) v = gelu_tanh(v);
                if (ACT == 2) v = (v > 0.f) ? v : 0.01f * v;
                if (SCALEQ) v = (gcol < 256) ? v * 0.18033688f : v;  // 0.125*log2(e)
                size_t off = (size_t)grow * ldc + gcol;
                if (RES) v += Rsd[off];
                if (OUTBF) ((u16*)Cout)[off] = f2bf(v);
                else       ((float*)Cout)[off] = v;
            }
        }
    }
}

// ---------------------------------------------------------------------------
// Full-row-width residual GEMM with fused LayerNorm epilogue (R8 v1, proven).
// N=256 fixed. X += A@Wt + bias (fp32); if LNOUT: Hb = LN(X_row)*ls+lb (bf16).
// BM=64, 4 waves, each wave owns 16 rows x 256 cols (acc[16] f32x4).
// Works for any M multiple of 64 (grid = M/64).
// ---------------------------------------------------------------------------
template<int LNOUT>
__global__ __launch_bounds__(256) void gemm_res_ln(
    const u16* __restrict__ A, int lda,
    const u16* __restrict__ Wt,                 // [256][K]
    const float* __restrict__ bias,
    float* __restrict__ X,                      // residual in/out (fp32)
    const float* __restrict__ ls, const float* __restrict__ lb,
    u16* __restrict__ Hb, int K)
{
    __shared__ u16 As[64*64];
    __shared__ u16 Bs[256*64];
    const int t = threadIdx.x, w = t >> 6;
    const int lane = t & 63, lo = lane & 15, hi = lane >> 4;
    const int bm = blockIdx.x * 64;
    f32x4 acc[16] = {};

    for (int k0 = 0; k0 < K; k0 += 64) {
        __syncthreads();
        #pragma unroll
        for (int i = 0; i < 2; ++i) {
            int id = i*256 + t;
            int row = id >> 3, c = id & 7, cs = c ^ (row & 7);
            gload_lds16(A + (size_t)(bm + row) * lda + k0 + cs*8,
                        &As[(i*256 + w*64)*8]);
        }
        #pragma unroll
        for (int i = 0; i < 8; ++i) {
            int id = i*256 + t;
            int row = id >> 3, c = id & 7, cs = c ^ (row & 7);
            gload_lds16(Wt + (size_t)row * K + k0 + cs*8,
                        &Bs[(i*256 + w*64)*8]);
        }
        __syncthreads();
        #pragma unroll
        for (int ks = 0; ks < 2; ++ks) {
            int arow = w*16 + lo;
            bf16x8 af = *(const bf16x8*)&As[arow*64 + (((ks*4 + hi) ^ (arow & 7)) * 8)];
            #pragma unroll
            for (int n = 0; n < 16; ++n) {
                int brow = n*16 + lo;
                bf16x8 bfr = *(const bf16x8*)&Bs[brow*64 + (((ks*4 + hi) ^ (brow & 7)) * 8)];
                acc[n] = __builtin_amdgcn_mfma_f32_16x16x32_bf16(af, bfr, acc[n], 0, 0, 0);
            }
        }
    }

    float bvv[16];
    #pragma unroll
    for (int n = 0; n < 16; ++n) bvv[n] = bias[n*16 + lo];

    float vv[4][16];
    float summ[4], sq[4];
    #pragma unroll
    for (int r = 0; r < 4; ++r) {
        int grow = bm + w*16 + hi*4 + r;
        float s_ = 0.f, q_ = 0.f;
        #pragma unroll
        for (int n = 0; n < 16; ++n) {
            float val = acc[n][r] + bvv[n] + X[(size_t)grow*256 + n*16 + lo];
            vv[r][n] = val;
            s_ += val; q_ += val*val;
        }
        #pragma unroll
        for (int n = 0; n < 16; ++n)
            X[(size_t)grow*256 + n*16 + lo] = vv[r][n];
        summ[r] = s_; sq[r] = q_;
    }
    if (LNOUT) {
        #pragma unroll
        for (int m = 1; m < 16; m <<= 1) {
            #pragma unroll
            for (int r = 0; r < 4; ++r) {
                summ[r] += __shfl_xor(summ[r], m);
                sq[r]   += __shfl_xor(sq[r], m);
            }
        }
        float lsv[16], lbv[16];
        #pragma unroll
        for (int n = 0; n < 16; ++n) { lsv[n] = ls[n*16+lo]; lbv[n] = lb[n*16+lo]; }
        #pragma unroll
        for (int r = 0; r < 4; ++r) {
            int grow = bm + w*16 + hi*4 + r;
            float mean = summ[r] * (1.f/256.f);
            float var  = sq[r] * (1.f/256.f) - mean*mean;
            float rstd = rsqrtf(var + 1e-5f);
            #pragma unroll
            for (int n = 0; n < 16; ++n) {
                float h = (vv[r][n] - mean)*rstd*lsv[n] + lbv[n];
                Hb[(size_t)grow*256 + n*16 + lo] = f2bf(h);
            }
        }
    }
}

// ---------------------------------------------------------------------------
// Softmax step (base-2 domain). See R7 notes.
// ---------------------------------------------------------------------------
template<bool MASK>
__device__ __forceinline__ void qk_softmax(
    f32x4 (&sacc)[4], float& mrow, float& lrow, f32x4 (&oacc)[4],
    unsigned* __restrict__ PW, int lo, int hi, int w)
{
    float p[4][4];
    float pmax = -1e30f;
    #pragma unroll
    for (int mf = 0; mf < 4; ++mf)
        #pragma unroll
        for (int r = 0; r < 4; ++r) {
            float s = sacc[mf][r];
            if (MASK) {
                int key = mf*16 + hi*4 + r;
                int q = w*16 + lo;
                if (key > q) s = -1e9f;
            }
            p[mf][r] = s;
            pmax = fmaxf(pmax, s);
        }
    pmax = fmaxf(pmax, __shfl_xor(pmax, 16));
    pmax = fmaxf(pmax, __shfl_xor(pmax, 32));
    if (!__all(pmax - mrow <= 11.5f)) {          // ~e^8 in base-2 domain
        float mnew = fmaxf(mrow, pmax);
        float alpha = __builtin_amdgcn_exp2f(mrow - mnew);
        mrow = mnew;
        lrow *= alpha;
        float al[4];
        #pragma unroll
        for (int r = 0; r < 4; ++r) al[r] = __shfl(alpha, hi*4 + r);
        #pragma unroll
        for (int n = 0; n < 4; ++n) {
            oacc[n][0] *= al[0]; oacc[n][1] *= al[1];
            oacc[n][2] *= al[2]; oacc[n][3] *= al[3];
        }
    }
    float rsum = 0.f;
    #pragma unroll
    for (int mf = 0; mf < 4; ++mf)
        #pragma unroll
        for (int r = 0; r < 4; ++r) {
            float e = __builtin_amdgcn_exp2f(p[mf][r] - mrow);
            p[mf][r] = e;
            rsum += e;
        }
    rsum += __shfl_xor(rsum, 16);
    rsum += __shfl_xor(rsum, 32);
    lrow += rsum;
    #pragma unroll
    for (int mf = 0; mf < 4; ++mf) {
        int c = mf*2 + (hi >> 1);
        int base2 = lo*32 + ((c ^ (lo & 7)) * 4) + (hi & 1) * 2;
        unsigned px, py;
        asm("v_cvt_pk_bf16_f32 %0, %1, %2" : "=v"(px) : "v"(p[mf][0]), "v"(p[mf][1]));
        asm("v_cvt_pk_bf16_f32 %0, %1, %2" : "=v"(py) : "v"(p[mf][2]), "v"(p[mf][3]));
        uint2 pk; pk.x = px; pk.y = py;
        *(uint2*)&PW[base2] = pk;
    }
}

// ---------------------------------------------------------------------------
// MFMA flash attention (R11 configuration — proven best).
// ---------------------------------------------------------------------------
__global__ __launch_bounds__(256, 4) void attn_mfma(
    const u16* __restrict__ QKV, const u16* __restrict__ Vt,
    u16* __restrict__ O)
{
    const int bid = blockIdx.x;
    const int bh = bid & 127;
    const int x  = bid >> 7;
    const int b  = bh >> 2, h = bh & 3;
    const int qta = x;
    const int qtb = 12 - x;
    const bool Bact = (x != 6);
    __shared__ u16 Kbuf[2][64*64];
    __shared__ u16 Vbuf[2][64*64];
    __shared__ u16 Plds[4][16*64];
    const int t = threadIdx.x, w = t >> 6;
    const int lane = t & 63, lo = lane & 15, hi = lane >> 4;

    bf16x8 qfA[2], qfB[2];
    {
        const u16* qp = QKV + ((size_t)(b*TT + qta*64 + w*16 + lo)) * 768 + h*64 + hi*8;
        qfA[0] = *(const bf16x8*)qp;
        qfA[1] = *(const bf16x8*)(qp + 32);
    }
    if (Bact) {
        const u16* qp = QKV + ((size_t)(b*TT + qtb*64 + w*16 + lo)) * 768 + h*64 + hi*8;
        qfB[0] = *(const bf16x8*)qp;
        qfB[1] = *(const bf16x8*)(qp + 32);
    }
    const u16* kB0 = QKV + ((size_t)b*TT) * 768 + 256 + h*64;
    const u16* vB0 = Vt + ((size_t)(b*NH + h) * 64) * TT;

    f32x4 oaccA[4] = {}, oaccB[4] = {};
    float mA = -1e30f, lA = 0.f, mB = -1e30f, lB = 0.f;
    unsigned* PW = (unsigned*)&Plds[w][0];
    const u16* Pw = &Plds[w][0];

    #define ATTN_STAGE(buf, kt) do { \
        _Pragma("unroll") \
        for (int i_ = 0; i_ < 2; ++i_) { \
            int id_ = i_*256 + t; \
            int row_ = id_ >> 3, c_ = id_ & 7, cs_ = c_ ^ (row_ & 7); \
            gload_lds16(kB0 + ((size_t)((kt)*64 + row_)) * 768 + cs_*8, \
                        &Kbuf[buf][(i_*256 + w*64)*8]); \
            gload_lds16(vB0 + (size_t)row_ * TT + (kt)*64 + cs_*8, \
                        &Vbuf[buf][(i_*256 + w*64)*8]); \
        } \
    } while (0)

    #define PV_TILE(Vc, oacc) do { \
        bf16x8 pf0 = *(const bf16x8*)&Pw[lo*64 + (((0 + hi) ^ (lo & 7)) * 8)]; \
        bf16x8 pf1 = *(const bf16x8*)&Pw[lo*64 + (((4 + hi) ^ (lo & 7)) * 8)]; \
        __builtin_amdgcn_s_setprio(1); \
        _Pragma("unroll") \
        for (int n_ = 0; n_ < 4; ++n_) { \
            int d_ = n_*16 + lo; \
            bf16x8 v0 = *(const bf16x8*)&Vc[d_*64 + (((0 + hi) ^ (d_ & 7)) * 8)]; \
            bf16x8 v1 = *(const bf16x8*)&Vc[d_*64 + (((4 + hi) ^ (d_ & 7)) * 8)]; \
            oacc[n_] = __builtin_amdgcn_mfma_f32_16x16x32_bf16(pf0, v0, oacc[n_], 0, 0, 0); \
            oacc[n_] = __builtin_amdgcn_mfma_f32_16x16x32_bf16(pf1, v1, oacc[n_], 0, 0, 0); \
        } \
        __builtin_amdgcn_s_setprio(0); \
    } while (0)

    const int ktmax = Bact ? qtb : qta;
    ATTN_STAGE(0, 0);
    int cur = 0;

    for (int kt = 0; kt <= ktmax; ++kt) {
        if (kt < ktmax) {
            ATTN_STAGE(cur ^ 1, kt + 1);      // 4 vm instrs, stay in flight
            __builtin_amdgcn_sched_barrier(0);
            asm volatile("s_waitcnt vmcnt(4)" ::: "memory");  // prev stage done
        } else {
            asm volatile("s_waitcnt vmcnt(0)" ::: "memory");
        }
        __builtin_amdgcn_s_barrier();          // cur tile visible to all waves
        __builtin_amdgcn_sched_barrier(0);
        const u16* Kc = &Kbuf[cur][0];
        const u16* Vc = &Vbuf[cur][0];
        const bool Aact = (kt <= qta);

        f32x4 saccA[4] = {}, saccB[4] = {};
        __builtin_amdgcn_s_setprio(1);
        #pragma unroll
        for (int mf = 0; mf < 4; ++mf) {
            int row = mf*16 + lo;
            bf16x8 k0 = *(const bf16x8*)&Kc[row*64 + (((0 + hi) ^ (row & 7)) * 8)];
            bf16x8 k1 = *(const bf16x8*)&Kc[row*64 + (((4 + hi) ^ (row & 7)) * 8)];
            if (Aact) {
                saccA[mf] = __builtin_amdgcn_mfma_f32_16x16x32_bf16(k0, qfA[0], saccA[mf], 0, 0, 0);
                saccA[mf] = __builtin_amdgcn_mfma_f32_16x16x32_bf16(k1, qfA[1], saccA[mf], 0, 0, 0);
            }
            if (Bact) {
                saccB[mf] = __builtin_amdgcn_mfma_f32_16x16x32_bf16(k0, qfB[0], saccB[mf], 0, 0, 0);
                saccB[mf] = __builtin_amdgcn_mfma_f32_16x16x32_bf16(k1, qfB[1], saccB[mf], 0, 0, 0);
            }
        }
        __builtin_amdgcn_s_setprio(0);

        if (Aact) {
            if (kt == qta) qk_softmax<true >(saccA, mA, lA, oaccA, PW, lo, hi, w);
            else           qk_softmax<false>(saccA, mA, lA, oaccA, PW, lo, hi, w);
            PV_TILE(Vc, oaccA);                // overlaps smB below (MFMA vs VALU)
        }
        if (Bact) {
            if (kt == qtb) qk_softmax<true >(saccB, mB, lB, oaccB, PW, lo, hi, w);
            else           qk_softmax<false>(saccB, mB, lB, oaccB, PW, lo, hi, w);
            PV_TILE(Vc, oaccB);
        }
        __builtin_amdgcn_sched_barrier(0);
        __builtin_amdgcn_s_barrier();          // all reads of cur done
        __builtin_amdgcn_sched_barrier(0);
        cur ^= 1;
    }
    #undef ATTN_STAGE
    #undef PV_TILE

    {
        float linv[4];
        #pragma unroll
        for (int r = 0; r < 4; ++r) linv[r] = 1.0f / __shfl(lA, hi*4 + r);
        #pragma unroll
        for (int n = 0; n < 4; ++n)
            #pragma unroll
            for (int r = 0; r < 4; ++r) {
                size_t row = (size_t)(b*TT + qta*64 + w*16 + hi*4 + r);
                O[row*256 + h*64 + n*16 + lo] = f2bf(oaccA[n][r] * linv[r]);
            }
    }
    if (Bact) {
        float linv[4];
        #pragma unroll
        for (int r = 0; r < 4; ++r) linv[r] = 1.0f / __shfl(lB, hi*4 + r);
        #pragma unroll
        for (int n = 0; n < 4; ++n)
            #pragma unroll
            for (int r = 0; r < 4; ++r) {
                size_t row = (size_t)(b*TT + qtb*64 + w*16 + hi*4 + r);
                O[row*256 + h*64 + n*16 + lo] = f2bf(oaccB[n][r] * linv[r]);
            }
    }
}

// ---------------------------------------------------------------------------
// fp32 GEMM (small matrices only). ACT: 0 none, 2 leaky
// ---------------------------------------------------------------------------
template<int ACT, bool RES>
__global__ __launch_bounds__(256) void gemm_f32(
    const float* __restrict__ A, const float* __restrict__ W,
    const float* __restrict__ bias, const float* __restrict__ Rsd,
    float* __restrict__ C, int M, int N, int K)
{
    __shared__ float As[16][68];
    __shared__ float Ws[16][68];
    const int bm = blockIdx.x * 64;
    const int bn = blockIdx.y * 64;
    const int t = threadIdx.x;
    const int tx = t & 15, ty = t >> 4;
    float c[4][4] = {};
    for (int k0 = 0; k0 < K; k0 += 16) {
        {
            int row = bm + (t >> 2);
            int kk = (t & 3) * 4;
            float4 a = make_float4(0.f, 0.f, 0.f, 0.f);
            if (row < M) a = *(const float4*)(A + (size_t)row * K + k0 + kk);
            int mm = t >> 2;
            As[kk+0][mm] = a.x; As[kk+1][mm] = a.y; As[kk+2][mm] = a.z; As[kk+3][mm] = a.w;
        }
        {
            int kr = t >> 4;
            int col = (t & 15) * 4;
            *(float4*)&Ws[kr][col] = *(const float4*)(W + (size_t)(k0 + kr) * N + bn + col);
        }
        __syncthreads();
        #pragma unroll
        for (int kk = 0; kk < 16; ++kk) {
            float4 a4 = *(const float4*)&As[kk][ty*4];
            float4 b4 = *(const float4*)&Ws[kk][tx*4];
            float av[4] = {a4.x, a4.y, a4.z, a4.w};
            float bb[4] = {b4.x, b4.y, b4.z, b4.w};
            #pragma unroll
            for (int i = 0; i < 4; ++i)
                #pragma unroll
                for (int j = 0; j < 4; ++j)
                    c[i][j] = fmaf(av[i], bb[j], c[i][j]);
        }
        __syncthreads();
    }
    float4 b4 = *(const float4*)(bias + bn + tx*4);
    float bvals[4] = {b4.x, b4.y, b4.z, b4.w};
    #pragma unroll
    for (int i = 0; i < 4; ++i) {
        int row = bm + ty*4 + i;
        if (row >= M) continue;
        float tmp[4];
        #pragma unroll
        for (int j = 0; j < 4; ++j) {
            float v = c[i][j] + bvals[j];
            if (ACT == 2) v = (v > 0.f) ? v : 0.01f * v;
            tmp[j] = v;
        }
        size_t off = (size_t)row * N + bn + tx*4;
        if (RES) {
            float4 r4 = *(const float4*)(Rsd + off);
            tmp[0] += r4.x; tmp[1] += r4.y; tmp[2] += r4.z; tmp[3] += r4.w;
        }
        *(float4*)(C + off) = make_float4(tmp[0], tmp[1], tmp[2], tmp[3]);
    }
}

// ---------------------------------------------------------------------------
// LayerNorm: fp32 in, bf16 out (used once, layer-0 ln1)
// ---------------------------------------------------------------------------
template<int OUTBF>
__global__ __launch_bounds__(256) void ln_kernel(const float* __restrict__ Xin,
    const float* __restrict__ sc, const float* __restrict__ bi,
    void* __restrict__ Y, int M)
{
    int row = blockIdx.x * 4 + (threadIdx.x >> 6);
    if (row >= M) return;
    int lane = threadIdx.x & 63;
    float4 xv = *(const float4*)(Xin + (size_t)row * DD + lane*4);
    float sum = xv.x + xv.y + xv.z + xv.w;
    float sq  = xv.x*xv.x + xv.y*xv.y + xv.z*xv.z + xv.w*xv.w;
    #pragma unroll
    for (int m = 32; m; m >>= 1) { sum += __shfl_xor(sum, m); sq += __shfl_xor(sq, m); }
    float mean = sum * (1.f/256.f);
    float var  = sq * (1.f/256.f) - mean*mean;
    float rs = rsqrtf(var + 1e-5f);
    float4 sv = *(const float4*)(sc + lane*4);
    float4 bv = *(const float4*)(bi + lane*4);
    float4 y;
    y.x = (xv.x - mean)*rs*sv.x + bv.x;
    y.y = (xv.y - mean)*rs*sv.y + bv.y;
    y.z = (xv.z - mean)*rs*sv.z + bv.z;
    y.w = (xv.w - mean)*rs*sv.w + bv.w;
    if (OUTBF) {
        ushort4 o; o.x = f2bf(y.x); o.y = f2bf(y.y); o.z = f2bf(y.z); o.w = f2bf(y.w);
        *(ushort4*)((u16*)Y + (size_t)row * DD + lane*4) = o;
    } else {
        *(float4*)((float*)Y + (size_t)row * DD + lane*4) = y;
    }
}

// ---------------------------------------------------------------------------
// Gather last-layer head rows: OG (bf16) = Ob[H_IDX], XG (fp32) = X[H_IDX]
// ---------------------------------------------------------------------------
__global__ __launch_bounds__(256) void gather_last(const u16* __restrict__ Ob,
    const float* __restrict__ X, u16* __restrict__ OG, float* __restrict__ XG)
{
    int idx = blockIdx.x * 256 + threadIdx.x;      // BB*NHID*64 = 131072
    int row = idx >> 6, c4 = (idx & 63) * 4;
    int b = row >> 6, i = row & 63;
    int tt = i*13 + 12;
    size_t src = ((size_t)(b*TT + tt)) * DD + c4;
    *(ushort4*)(OG + (size_t)row*DD + c4) = *(const ushort4*)(Ob + src);
    *(float4*)(XG + (size_t)row*DD + c4)  = *(const float4*)(X + src);
}

// ---------------------------------------------------------------------------
__global__ __launch_bounds__(256) void manual_pool(
    const float* __restrict__ em, const float* __restrict__ mk_w, const float* __restrict__ mk_b,
    const float* __restrict__ mv_w, const float* __restrict__ mv_b,
    float* __restrict__ MK, float* __restrict__ MV)
{
    int bs = blockIdx.x;
    const float* base = em + (size_t)bs * LMM * DD;
    __shared__ float ems[LMM][DD];
    __shared__ float wk_s[DD], wv_s[DD];
    __shared__ float sk[LMM], sv[LMM];
    __shared__ float inv2[2];
    int t = threadIdx.x;
    for (int i = t; i < LMM*DD/4; i += 256)
        ((float4*)&ems[0][0])[i] = ((const float4*)base)[i];
    wk_s[t] = mk_w[t];
    wv_s[t] = mv_w[t];
    __syncthreads();
    if (t < LMM) {
        float dk = 0.f, dv = 0.f;
        for (int d = 0; d < DD; ++d) {
            float e = ems[t][d];
            dk = fmaf(e, wk_s[d], dk);
            dv = fmaf(e, wv_s[d], dv);
        }
        sk[t] = dk + mk_b[0];
        sv[t] = dv + mv_b[0];
    }
    __syncthreads();
    if (t == 0) {
        float mk_ = -1e30f, mv_ = -1e30f;
        for (int l = 0; l < LMM; ++l) { mk_ = fmaxf(mk_, sk[l]); mv_ = fmaxf(mv_, sv[l]); }
        float sks = 0.f, svs = 0.f;
        for (int l = 0; l < LMM; ++l) {
            float ek = expf(sk[l]-mk_); sk[l] = ek; sks += ek;
            float ev = expf(sv[l]-mv_); sv[l] = ev; svs += ev;
        }
        inv2[0] = 1.f/sks; inv2[1] = 1.f/svs;
    }
    __syncthreads();
    float ak = 0.f, avv = 0.f;
    for (int l = 0; l < LMM; ++l) {
        float e = ems[l][t];
        ak  = fmaf(sk[l], e, ak);
        avv = fmaf(sv[l], e, avv);
    }
    MK[(size_t)bs*DD + t] = ak  * inv2[0];
    MV[(size_t)bs*DD + t] = avv * inv2[1];
}

__device__ __forceinline__ int qidx_to_t(int qi) {
    int blk = qi / 3, r = qi - blk*3;
    return blk*13 + (r == 0 ? 1 : (r == 1 ? 4 : 7));
}

__global__ void embed_kernel(const int* __restrict__ tokens,
    const float* __restrict__ emb_a, const float* __restrict__ emb_o,
    const float* __restrict__ pos, float* __restrict__ X)
{
    int idx = blockIdx.x * 256 + threadIdx.x;
    if (idx >= BT * 64) return;
    int row = idx >> 6;
    int c4 = (idx & 63) * 4;
    int tt = row % TT;
    int tok = tokens[row];
    const float* src = (tt % 13 == 0) ? (emb_a + tok * DD) : (emb_o + (size_t)tok * DD);
    float4 e = *(const float4*)(src + c4);
    float4 p = *(const float4*)(pos + (size_t)tt * DD + c4);
    *(float4*)(X + (size_t)row * DD + c4) = make_float4(e.x+p.x, e.y+p.y, e.z+p.z, e.w+p.w);
}

// Q positions are never action positions -> embeds[Q_IDX] = emb_obs[tokens]; bf16 out
__global__ void gather_q_kernel(const int* __restrict__ tokens,
    const float* __restrict__ emb_o, u16* __restrict__ Qin)
{
    int idx = blockIdx.x * 256 + threadIdx.x;
    if (idx >= BB * NQ * 64) return;
    int row = idx >> 6, c4 = (idx & 63) * 4;
    int b = row / NQ, qi = row - b*NQ;
    int tt = qidx_to_t(qi);
    int tok = tokens[b*TT + tt];
    float4 e = *(const float4*)(emb_o + (size_t)tok*DD + c4);
    ushort4 o; o.x = f2bf(e.x); o.y = f2bf(e.y); o.z = f2bf(e.z); o.w = f2bf(e.w);
    *(ushort4*)(Qin + (size_t)row*DD + c4) = o;
}

__global__ void scatter_av_kernel(const float* __restrict__ AVp, float* __restrict__ X)
{
    int idx = blockIdx.x * 256 + threadIdx.x;
    if (idx >= BB * NQ * 64) return;
    int row = idx >> 6, c4 = (idx & 63)*4;
    int b = row / NQ, qi = row - b*NQ;
    int tt = qidx_to_t(qi);
    float* xp = X + ((size_t)b*TT + tt)*DD + c4;
    float4 a = *(const float4*)(AVp + (size_t)row*DD + c4);
    float4 xv = *(const float4*)xp;
    *(float4*)xp = make_float4(xv.x+a.x, xv.y+a.y, xv.z+a.z, xv.w+a.w);
}

// 3-slot cross attention; Qm bf16, K/V fp32, AV bf16
__global__ __launch_bounds__(256) void manual_attn(
    const u16* __restrict__ Qm, const float* __restrict__ Kp,
    const float* __restrict__ Vp, u16* __restrict__ AV)
{
    int row = blockIdx.x * 4 + (threadIdx.x >> 6);
    int lane = threadIdx.x & 63;
    int b = row / NQ;
    ushort4 qv = *(const ushort4*)(Qm + (size_t)row * DD + lane*4);
    float qx = bf2f(qv.x), qy = bf2f(qv.y), qz = bf2f(qv.z), qw = bf2f(qv.w);
    float s[3];
    #pragma unroll
    for (int j = 0; j < 3; ++j) {
        float4 kv = *(const float4*)(Kp + ((size_t)b*SS + j)*DD + lane*4);
        float d = qx*kv.x + qy*kv.y + qz*kv.z + qw*kv.w;
        #pragma unroll
        for (int m = 32; m; m >>= 1) d += __shfl_xor(d, m);
        s[j] = d * 0.0625f;
    }
    float mx = fmaxf(s[0], fmaxf(s[1], s[2]));
    float p0 = expf(s[0]-mx), p1 = expf(s[1]-mx), p2 = expf(s[2]-mx);
    float inv = 1.f/(p0+p1+p2);
    p0 *= inv; p1 *= inv; p2 *= inv;
    float4 v0 = *(const float4*)(Vp + ((size_t)b*SS+0)*DD + lane*4);
    float4 v1 = *(const float4*)(Vp + ((size_t)b*SS+1)*DD + lane*4);
    float4 v2 = *(const float4*)(Vp + ((size_t)b*SS+2)*DD + lane*4);
    ushort4 o;
    o.x = f2bf(p0*v0.x + p1*v1.x + p2*v2.x);
    o.y = f2bf(p0*v0.y + p1*v1.y + p2*v2.y);
    o.z = f2bf(p0*v0.z + p1*v1.z + p2*v2.z);
    o.w = f2bf(p0*v0.w + p1*v1.w + p2*v2.w);
    *(ushort4*)(AV + (size_t)row * DD + lane*4) = o;
}

// final head matmuls + softmax; A2/V2 bf16
__global__ __launch_bounds__(64) void head_final(
    const u16* __restrict__ A2, const float* __restrict__ w3a, const float* __restrict__ b3a,
    const u16* __restrict__ V2, const float* __restrict__ w3v, const float* __restrict__ b3v,
    float* __restrict__ out)
{
    int row = blockIdx.x;
    int lane = threadIdx.x;
    ushort4 av = *(const ushort4*)(A2 + (size_t)row*DD + lane*4);
    float a0 = bf2f(av.x), a1 = bf2f(av.y), a2 = bf2f(av.z), a3 = bf2f(av.w);
    float lg[5];
    #pragma unroll
    for (int j = 0; j < 5; ++j) {
        float p = a0*w3a[(lane*4+0)*5+j] + a1*w3a[(lane*4+1)*5+j]
                + a2*w3a[(lane*4+2)*5+j] + a3*w3a[(lane*4+3)*5+j];
        #pragma unroll
        for (int m = 32; m; m >>= 1) p += __shfl_xor(p, m);
        lg[j] = p + b3a[j];
    }
    ushort4 vv = *(const ushort4*)(V2 + (size_t)row*DD + lane*4);
    float pv = bf2f(vv.x)*w3v[lane*4+0] + bf2f(vv.y)*w3v[lane*4+1]
             + bf2f(vv.z)*w3v[lane*4+2] + bf2f(vv.w)*w3v[lane*4+3];
    #pragma unroll
    for (int m = 32; m; m >>= 1) pv += __shfl_xor(pv, m);
    if (lane == 0) {
        float mx = lg[0];
        #pragma unroll
        for (int j = 1; j < 5; ++j) mx = fmaxf(mx, lg[j]);
        float e[5], ssum = 0.f;
        #pragma unroll
        for (int j = 0; j < 5; ++j) { e[j] = expf(lg[j]-mx); ssum += e[j]; }
        float inv = 1.f/ssum;
        #pragma unroll
        for (int j = 0; j < 5; ++j) out[(size_t)row*5 + j] = e[j]*inv;
        out[(size_t)BB*NHID*5 + row] = pv + b3v[0];
    }
}

// ---------------------------------------------------------------------------
extern "C" void kernel_launch(void* const* d_in, const int* in_sizes, int n_in,
                              void* d_out, int out_size, void* d_ws, size_t ws_size,
                              hipStream_t stream)
{
    (void)in_sizes; (void)n_in; (void)out_size; (void)ws_size;
    const int*   tokens = (const int*)d_in[0];
    const float* em     = (const float*)d_in[1];
    const float* emb_a  = (const float*)d_in[2];
    const float* emb_o  = (const float*)d_in[3];
    const float* pos    = (const float*)d_in[4];
    const float* mk_w   = (const float*)d_in[5];
    const float* mk_b   = (const float*)d_in[6];
    const float* mv_w   = (const float*)d_in[7];
    const float* mv_b   = (const float*)d_in[8];
    const float* ma_wq  = (const float*)d_in[9];
    const float* ma_bq  = (const float*)d_in[10];
    const float* ma_wk  = (const float*)d_in[11];
    const float* ma_bk  = (const float*)d_in[12];
    const float* ma_wv  = (const float*)d_in[13];
    const float* ma_bv  = (const float*)d_in[14];
    const float* ma_wo  = (const float*)d_in[15];
    const float* ma_bo  = (const float*)d_in[16];
    const float* ln1_s  = (const float*)d_in[17];
    const float* ln1_b  = (const float*)d_in[18];
    const float* wq     = (const float*)d_in[19];
    const float* bq     = (const float*)d_in[20];
    const float* wk     = (const float*)d_in[21];
    const float* bk     = (const float*)d_in[22];
    const float* wv     = (const float*)d_in[23];
    const float* bv     = (const float*)d_in[24];
    const float* wo     = (const float*)d_in[25];
    const float* bo     = (const float*)d_in[26];
    const float* ln2_s  = (const float*)d_in[27];
    const float* ln2_b  = (const float*)d_in[28];
    const float* w1     = (const float*)d_in[29];
    const float* b1     = (const float*)d_in[30];
    const float* w2     = (const float*)d_in[31];
    const float* b2     = (const float*)d_in[32];
    const float* lnf_s  = (const float*)d_in[33];
    const float* lnf_b  = (const float*)d_in[34];
    const float* ha_w1  = (const float*)d_in[35];
    const float* ha_b1  = (const float*)d_in[36];
    const float* ha_w2  = (const float*)d_in[37];
    const float* ha_b2  = (const float*)d_in[38];
    const float* ha_w3  = (const float*)d_in[39];
    const float* ha_b3  = (const float*)d_in[40];
    const float* hv_w1  = (const float*)d_in[41];
    const float* hv_b1  = (const float*)d_in[42];
    const float* hv_w2  = (const float*)d_in[43];
    const float* hv_b2  = (const float*)d_in[44];
    const float* hv_w3  = (const float*)d_in[45];
    const float* hv_b3  = (const float*)d_in[46];

    char* base = (char*)d_ws;
    const size_t OFF_X    = 0;
    const size_t OFF_HB   = 27262976;   // X: BT*256*4
    const size_t OFF_QKV  = 40894464;   // Hb: BT*256*2
    const size_t OFF_VT   = 81788928;   // QKV: BT*768*2
    const size_t OFF_OB   = 95420416;   // Vt: 32*4*64*832*2
    const size_t OFF_MID  = 109051904;  // Ob: BT*256*2
    const size_t OFF_W    = 163577856;  // MID: BT*1024*2

    float* X    = (float*)(base + OFF_X);
    u16*   Hb   = (u16*)(base + OFF_HB);
    u16*   QKVb = (u16*)(base + OFF_QKV);
    u16*   Vt   = (u16*)(base + OFF_VT);
    u16*   Ob   = (u16*)(base + OFF_OB);
    u16*   MID  = (u16*)(base + OFF_MID);
    u16*   Wqkv = (u16*)(base + OFF_W);                 // [NL][768][256]
    u16*   Wo   = Wqkv + (size_t)NLAYER*768*256;        // [NL][256][256]
    u16*   W1t  = Wo   + (size_t)NLAYER*256*256;        // [NL][1024][256]
    u16*   W2t  = W1t  + (size_t)NLAYER*1024*256;       // [NL][256][1024]
    float* bqkv = (float*)(W2t + (size_t)NLAYER*256*1024);  // [NL][768]
    u16*   Wmq  = (u16*)(bqkv + NLAYER*768);            // [256][256]
    u16*   Wmo  = Wmq  + 256*256;
    u16*   Wha1 = Wmo  + 256*256;
    u16*   Wha2 = Wha1 + 256*256;
    u16*   Whv1 = Wha2 + 256*256;
    u16*   Whv2 = Whv1 + 256*256;

    // aliases into regions dead during pre/post stages:
    u16*   MQIN = (u16*)(base + OFF_MID);
    u16*   MQ   = MQIN + (size_t)BB*NQ*DD;
    u16*   MAV  = MQ   + (size_t)BB*NQ*DD;
    float* MAVP = (float*)(MAV + (size_t)BB*NQ*DD);
    float* MKp  = (float*)(base + OFF_VT);
    float* MVp  = MKp + BB*SS*DD;
    float* KP   = MVp + BB*SS*DD;
    float* VP   = KP  + BB*SS*DD;
    u16*   HXNb = (u16*)(base + OFF_MID);               // post-stage (MID dead)
    u16*   A1b  = HXNb + (size_t)BB*NHID*DD;
    u16*   A2b  = A1b  + (size_t)BB*NHID*DD;
    u16*   V1b  = A2b  + (size_t)BB*NHID*DD;
    u16*   V2b  = V1b  + (size_t)BB*NHID*DD;
    // last-layer gathered buffers (further into dead MID region):
    u16*   OG   = V2b  + (size_t)BB*NHID*DD;            // [2048][256] bf16
    float* XG   = (float*)(OG + (size_t)BB*NHID*DD);    // [2048][256] fp32
    u16*   HbG  = (u16*)(XG + (size_t)BB*NHID*DD);      // [2048][256] bf16
    u16*   MIDG = HbG + (size_t)BB*NHID*DD;             // [2048][1024] bf16

    // ---- weight conversion (single launch) ----
    wtrans_all<<<3468, 256, 0, stream>>>(wq, wk, wv, wo, w1, w2, ma_wq, ma_wo,
                                         ha_w1, ha_w2, hv_w1, hv_w2,
                                         bq, bk, bv,
                                         Wqkv, Wo, W1t, W2t, Wmq, Wmo,
                                         Wha1, Wha2, Whv1, Whv2, bqkv);

    #define GEMMF(ACT, RES, A_, W_, BIAS_, R_, C_, M_, N_, K_) \
        gemm_f32<ACT, RES><<<dim3(((M_)+63)/64, (N_)/64), 256, 0, stream>>>(A_, W_, BIAS_, R_, C_, M_, N_, K_)

    // ---- pre-stage ----
    manual_pool<<<BB*SS, 256, 0, stream>>>(em, mk_w, mk_b, mv_w, mv_b, MKp, MVp);
    embed_kernel<<<(BT*64)/256, 256, 0, stream>>>(tokens, emb_a, emb_o, pos, X);
    gather_q_kernel<<<(BB*NQ*64)/256, 256, 0, stream>>>(tokens, emb_o, MQIN);
    gemm_bf16<0,0,1,0,0,4><<<96, 256, 0, stream>>>(
        MQIN, 256, Wmq, ma_bq, (const float*)nullptr, MQ, 256, 256, (u16*)nullptr, 48);
    GEMMF(0, false, MKp,  ma_wk, ma_bk, (const float*)nullptr, KP, BB*SS, DD, DD);
    GEMMF(0, false, MVp,  ma_wv, ma_bv, (const float*)nullptr, VP, BB*SS, DD, DD);
    manual_attn<<<(BB*NQ)/4, 256, 0, stream>>>(MQ, KP, VP, MAV);
    gemm_bf16<0,0,0,0,0,4><<<96, 256, 0, stream>>>(
        MAV, 256, Wmo, ma_bo, (const float*)nullptr, MAVP, 256, 256, (u16*)nullptr, 48);
    scatter_av_kernel<<<(BB*NQ*64)/256, 256, 0, stream>>>(MAVP, X);

    // ---- transformer layers (bf16 MFMA; LN fused into residual GEMMs) ----
    ln_kernel<1><<<BT/4, 256, 0, stream>>>(X, ln1_s, ln1_b, Hb, BT);  // layer-0 ln1
    for (int l = 0; l < NLAYER; ++l) {
        gemm_bf16<0,0,1,1,1,4><<<1248, 256, 0, stream>>>(
            Hb, 256, Wqkv + (size_t)l*768*256, bqkv + l*768,
            (const float*)nullptr, QKVb, 768, 256, Vt, 208);
        attn_mfma<<<896, 256, 0, stream>>>(QKVb, Vt, Ob);
        if (l < NLAYER-1) {
            gemm_res_ln<1><<<416, 256, 0, stream>>>(
                Ob, 256, Wo + (size_t)l*256*256, bo + l*DD, X,
                ln2_s + l*DD, ln2_b + l*DD, Hb, 256);
            gemm_bf16<1,0,1,0,0,4><<<1664, 256, 0, stream>>>(
                Hb, 256, W1t + (size_t)l*1024*256, b1 + l*FF,
                (const float*)nullptr, MID, 1024, 256, (u16*)nullptr, 208);
            gemm_res_ln<1><<<416, 256, 0, stream>>>(
                MID, 1024, W2t + (size_t)l*256*1024, b2 + l*DD, X,
                ln1_s + (l+1)*DD, ln1_b + (l+1)*DD, Hb, 1024);
        } else {
            // Last layer: only H_IDX rows (t%13==12) are consumed downstream.
            gather_last<<<(BB*NHID*64)/256, 256, 0, stream>>>(Ob, X, OG, XG);
            gemm_res_ln<1><<<(BB*NHID)/64, 256, 0, stream>>>(
                OG, 256, Wo + (size_t)l*256*256, bo + l*DD, XG,
                ln2_s + l*DD, ln2_b + l*DD, HbG, 256);
            gemm_bf16<1,0,1,0,0,4><<<128, 256, 0, stream>>>(
                HbG, 256, W1t + (size_t)l*1024*256, b1 + l*FF,
                (const float*)nullptr, MIDG, 1024, 256, (u16*)nullptr, 16);
            gemm_res_ln<1><<<(BB*NHID)/64, 256, 0, stream>>>(
                MIDG, 1024, W2t + (size_t)l*256*1024, b2 + l*DD, XG,
                lnf_s, lnf_b, HXNb, 1024);
        }
    }

    // ---- post-stage (bf16 MFMA heads; HXNb already holds lnf output) ----
    gemm_bf16<2,0,1,0,0,4><<<32, 256, 0, stream>>>(
        HXNb, 256, Wha1, ha_b1, (const float*)nullptr, A1b, 256, 256, (u16*)nullptr, 16);
    gemm_bf16<2,0,1,0,0,4><<<32, 256, 0, stream>>>(
        A1b, 256, Wha2, ha_b2, (const float*)nullptr, A2b, 256, 256, (u16*)nullptr, 16);
    gemm_bf16<2,0,1,0,0,4><<<32, 256, 0, stream>>>(
        HXNb, 256, Whv1, hv_b1, (const float*)nullptr, V1b, 256, 256, (u16*)nullptr, 16);
    gemm_bf16<2,0,1,0,0,4><<<32, 256, 0, stream>>>(
        V1b, 256, Whv2, hv_b2, (const float*)nullptr, V2b, 256, 256, (u16*)nullptr, 16);
    head_final<<<BB*NHID, 64, 0, stream>>>(A2b, ha_w3, ha_b3, V2b, hv_w3, hv_b3, (float*)d_out);
    #undef GEMMF
}